// Round 14
// baseline (109.589 us; speedup 1.0000x reference)
//
#include <hip/hip_runtime.h>
#include <stdint.h>

typedef __attribute__((ext_vector_type(8))) short short8;
typedef __attribute__((ext_vector_type(4))) float f32x4;
typedef __attribute__((ext_vector_type(8))) _Float16 half8;

#define QSCALE 21.1666667f    /* 127/6 : q,k,v quantize */
#define VSCALE 0.04724409449f /* 6/127 : v dequant */
#define SCONST 9.86413e-5f    /* (6/127)^2 / sqrt(512) : score dequant */

static __device__ __forceinline__ unsigned short f2bf(float f) {
  unsigned int u = __float_as_uint(f);
  u += 0x7FFFu + ((u >> 16) & 1u);
  return (unsigned short)(u >> 16);
}
static __device__ __forceinline__ float bf2f(unsigned short h) {
  return __uint_as_float(((unsigned int)h) << 16);
}
static __device__ __forceinline__ unsigned short f2h(float f) {
  _Float16 h = (_Float16)f;
  return __builtin_bit_cast(unsigned short, h);
}
static __device__ __forceinline__ signed char q8(float v) {
  float sv = fminf(fmaxf(v * QSCALE, -127.f), 127.f);
  return (signed char)(int)rintf(sv);
}
static __device__ __forceinline__ unsigned char qu8(float v) {
  return (unsigned char)(int)rintf(fminf(fmaxf(v * QSCALE + 128.f, 0.f), 255.f));
}
// LLVM pattern-matches this to v_cvt_f32_ubyteN
static __device__ __forceinline__ float ub(unsigned int x, int n) {
  return (float)((x >> (8 * n)) & 0xffu);
}

#define GLD16(gp, lp) __builtin_amdgcn_global_load_lds( \
    (__attribute__((address_space(1))) void*)(gp), \
    (__attribute__((address_space(3))) void*)(lp), 16, 0, 0)

// --------- prep: x->f16 (2048) | Wq/Wk/Wv transposes (768) -----------------
__global__ __launch_bounds__(256) void k_prep(
    const float* __restrict__ x, unsigned short* __restrict__ xb,
    const float* __restrict__ Wq, const float* __restrict__ Wk,
    const float* __restrict__ Wv, unsigned short* __restrict__ wqkvt) {
  __shared__ float tile[32][33];
  const int bid = blockIdx.x;
  const int t = threadIdx.x;
  if (bid < 2048) {
    const int xcd = bid & 7;
    const int bb = xcd >> 1;
    const int s = ((bid >> 3) << 1) | (xcd & 1);
    const long row = ((long)bb << 11) | ((long)s << 2) | (t >> 6);
    const int lane = t & 63;
    const float4* p = (const float4*)(x + row * 512 + lane * 8);
    float4 a = p[0], b = p[1];
    short8 v;
    v[0] = (short)f2h(a.x); v[1] = (short)f2h(a.y);
    v[2] = (short)f2h(a.z); v[3] = (short)f2h(a.w);
    v[4] = (short)f2h(b.x); v[5] = (short)f2h(b.y);
    v[6] = (short)f2h(b.z); v[7] = (short)f2h(b.w);
    *(short8*)(xb + row * 512 + lane * 8) = v;
    return;
  }
  const int lb = bid - 2048;       // 0..767
  const int m = lb >> 8;           // 0,1,2 -> Wq,Wk,Wv
  const float* src = m == 0 ? Wq : (m == 1 ? Wk : Wv);
  unsigned short* dst = wqkvt + (long)m * 512 * 512;
  const int local = lb & 255;
  const int c0 = (local & 15) << 5;
  const int r0 = (local >> 4) << 5;
  const int tx = t & 31, ty = t >> 5;
#pragma unroll
  for (int i = 0; i < 4; i++)
    tile[ty + i * 8][tx] = src[(long)(r0 + ty + i * 8) * 512 + c0 + tx];
  __syncthreads();
#pragma unroll
  for (int i = 0; i < 4; i++)
    dst[(long)(c0 + ty + i * 8) * 512 + r0 + tx] = f2h(tile[tx][ty + i * 8]);
}

// -- G1x: qkv GEMM (768) | adj-mask gather (1024) | Wo/W1/W2 transpose (1024)
// GEMM: f16 MFMA 128x128, BK=32, dbuf, 32 KB LDS -> ~5 blocks/CU so the
// latency-bound gather/transpose blocks co-reside and hide under MFMA.
__global__ __launch_bounds__(256) void k_g1x(
    const unsigned short* __restrict__ A, const unsigned short* __restrict__ Bt,
    const float* __restrict__ bq, const float* __restrict__ bk,
    const float* __restrict__ bv, signed char* __restrict__ qk8,
    unsigned char* __restrict__ v8,
    const float* __restrict__ adj, const int* __restrict__ inxs,
    float* __restrict__ maskb,
    const float* __restrict__ Wo, const float* __restrict__ W1,
    const float* __restrict__ W2, unsigned short* __restrict__ wot,
    unsigned short* __restrict__ w1t, unsigned short* __restrict__ w2t) {
  const int K = 512;
  __shared__ unsigned short As[2][128 * 32];
  __shared__ unsigned short Bs[2][128 * 32];
  const int t = threadIdx.x;
  const int bid = blockIdx.x;

  if (bid >= 768) {
    const int eb = bid - 768;
    if (eb < 1024) {
      // adj-mask gather: 8 rows/block, one lane per (row,kk)
      const int xcd = eb & 7;
      const int bb = xcd >> 1;
      const int s = ((eb >> 3) << 1) | (xcd & 1);
      const long row = ((long)bb << 11) | ((long)s << 3) | (t >> 5);
      const int kk = t & 31;
      const int idx = inxs[row * 32 + kk];
      const float a = adj[row * 2048 + idx];
      maskb[row * 32 + kk] = a > 0.f ? 0.f : -1e22f;
      return;
    }
    // Wo/W1/W2 transpose, fp32 [R][C] -> bf16 [C][R], 32x32 tiles
    float(*tile)[33] = (float(*)[33]) & As[0][0];  // alias gemm LDS (4.2 KB)
    const int lb = eb - 1024;  // 0..1023
    const float* src;
    unsigned short* dst;
    int R, C, local;
    if (lb < 256) { src = Wo; dst = wot; R = 512; C = 512; local = lb; }
    else if (lb < 640) { src = W1; dst = w1t; R = 512; C = 768; local = lb - 256; }
    else { src = W2; dst = w2t; R = 768; C = 512; local = lb - 640; }
    const int ntx = C >> 5;
    const int c0 = (local % ntx) << 5;
    const int r0 = (local / ntx) << 5;
    const int tx = t & 31, ty = t >> 5;
#pragma unroll
    for (int i = 0; i < 4; i++)
      tile[ty + i * 8][tx] = src[(long)(r0 + ty + i * 8) * C + c0 + tx];
    __syncthreads();
#pragma unroll
    for (int i = 0; i < 4; i++)
      dst[(long)(c0 + ty + i * 8) * R + r0 + tx] = f2bf(tile[tx][ty + i * 8]);
    return;
  }

  // ---------------- GEMM path (bid 0..767) ----------------
  const int lane = t & 63;
  const int w = t >> 6;
  const int wr = w >> 1, wc = w & 1;
  const int xcd = bid & 7;
  const int bb = xcd >> 1;
  const int s = ((bid >> 3) << 1) | (xcd & 1);  // 0..191
  const int m0 = (bb * 16 + s / 12) * 128;
  const int n0 = (s % 12) * 128;

  f32x4 acc[4][4];
#pragma unroll
  for (int mi = 0; mi < 4; mi++)
#pragma unroll
    for (int ni = 0; ni < 4; ni++) {
      f32x4 z = {0.f, 0.f, 0.f, 0.f};
      acc[mi][ni] = z;
    }

  // BK=32 tile: 128x32 = 512 x 16B chunks; 2 A-chunks + 2 B-chunks per thread.
  // Row = c>>2, chunk j = c&3; source pre-swizzled by j^((r>>1)&3) so the
  // swizzled ds_read lands on distinct 4-bank groups (2-way alias = free).
  auto stage = [&](int buf, int k0) {
#pragma unroll
    for (int i = 0; i < 2; i++) {
      const int c = t + i * 256;
      const int r = c >> 2, j = c & 3;
      GLD16(A + (long)(m0 + r) * K + k0 + ((j ^ ((r >> 1) & 3)) << 3), &As[buf][c * 8]);
    }
#pragma unroll
    for (int i = 0; i < 2; i++) {
      const int c = t + i * 256;
      const int r = c >> 2, j = c & 3;
      GLD16(Bt + (long)(n0 + r) * K + k0 + ((j ^ ((r >> 1) & 3)) << 3), &Bs[buf][c * 8]);
    }
  };

  const int nt = K >> 5;  // 16
  stage(0, 0);
  for (int tt = 0; tt < nt; ++tt) {
    const int cur = tt & 1;
    if (tt + 1 < nt) {
      stage(cur ^ 1, (tt + 1) << 5);
      asm volatile("s_waitcnt vmcnt(4)" ::: "memory");
    } else {
      asm volatile("s_waitcnt vmcnt(0)" ::: "memory");
    }
    __builtin_amdgcn_s_barrier();

    const int jj = lane >> 4;
    short8 af[4], bf[4];
#pragma unroll
    for (int mi = 0; mi < 4; mi++) {
      const int r = wr * 64 + mi * 16 + (lane & 15);
      af[mi] = *(const short8*)&As[cur][r * 32 + ((jj ^ ((r >> 1) & 3)) << 3)];
    }
#pragma unroll
    for (int ni = 0; ni < 4; ni++) {
      const int r = wc * 64 + ni * 16 + (lane & 15);
      bf[ni] = *(const short8*)&Bs[cur][r * 32 + ((jj ^ ((r >> 1) & 3)) << 3)];
    }
#pragma unroll
    for (int mi = 0; mi < 4; mi++)
#pragma unroll
      for (int ni = 0; ni < 4; ni++)
        acc[mi][ni] = __builtin_amdgcn_mfma_f32_16x16x32_f16(
            __builtin_bit_cast(half8, af[mi]), __builtin_bit_cast(half8, bf[ni]),
            acc[mi][ni], 0, 0, 0);
    asm volatile("s_waitcnt lgkmcnt(0)" ::: "memory");
    __builtin_amdgcn_s_barrier();
  }

  const int lr = (lane >> 4) * 4;
  const int lc = lane & 15;
  if (n0 < 1024) {  // q,k -> int8
#pragma unroll
    for (int mi = 0; mi < 4; mi++) {
#pragma unroll
      for (int ni = 0; ni < 4; ni++) {
        const int col = n0 + wc * 64 + ni * 16 + lc;
        const float bvv = col < 512 ? bq[col] : bk[col - 512];
#pragma unroll
        for (int r = 0; r < 4; r++) {
          const int row = m0 + wr * 64 + mi * 16 + lr + r;
          qk8[(long)row * 1024 + col] = q8(acc[mi][ni][r] + bvv);
        }
      }
    }
  } else {  // v -> uint8 fixed scale, bias 128
#pragma unroll
    for (int mi = 0; mi < 4; mi++) {
#pragma unroll
      for (int ni = 0; ni < 4; ni++) {
        const int col = n0 + wc * 64 + ni * 16 + lc;
        const float bvv = bv[col - 1024];
#pragma unroll
        for (int r = 0; r < 4; r++) {
          const int row = m0 + wr * 64 + mi * 16 + lr + r;
          v8[(long)row * 512 + (col - 1024)] = qu8(acc[mi][ni][r] + bvv);
        }
      }
    }
  }
}

// ------- bf16 MFMA GEMM, 128x64 tile, BK=32, dbuf, 24 KB LDS --------------
template <int EPI>
__global__ __launch_bounds__(256) void k_gemm(const unsigned short* __restrict__ A,
                                              const unsigned short* __restrict__ Bt,
                                              const float* __restrict__ bias,
                                              unsigned short* __restrict__ C,
                                              int M, int N, int K) {
  __shared__ unsigned short As[2][128 * 32];
  __shared__ unsigned short Bs[2][64 * 32];
  const int t = threadIdx.x;
  const int lane = t & 63;
  const int w = t >> 6;
  const int wr = w >> 1, wc = w & 1;
  const int lin = blockIdx.x;
  const int xcd = lin & 7;
  const int bb = xcd >> 1;
  const int nx = N >> 6;
  const int s = ((lin >> 3) << 1) | (xcd & 1);
  const int m0 = (bb * 16 + s / nx) * 128;
  const int n0 = (s % nx) * 64;

  f32x4 acc[4][2];
#pragma unroll
  for (int mi = 0; mi < 4; mi++)
#pragma unroll
    for (int ni = 0; ni < 2; ni++) {
      f32x4 z = {0.f, 0.f, 0.f, 0.f};
      acc[mi][ni] = z;
    }

  auto stage = [&](int buf, int k0) {
#pragma unroll
    for (int i = 0; i < 2; i++) {
      const int c = t + i * 256;
      const int r = c >> 2, j = c & 3;
      GLD16(A + (long)(m0 + r) * K + k0 + ((j ^ ((r >> 1) & 3)) << 3), &As[buf][c * 8]);
    }
    {
      const int c = t;  // 64x32 = 256 chunks, 1 per thread
      const int r = c >> 2, j = c & 3;
      GLD16(Bt + (long)(n0 + r) * K + k0 + ((j ^ ((r >> 1) & 3)) << 3), &Bs[buf][c * 8]);
    }
  };

  const int nt = K >> 5;
  stage(0, 0);
  for (int tt = 0; tt < nt; ++tt) {
    const int cur = tt & 1;
    if (tt + 1 < nt) {
      stage(cur ^ 1, (tt + 1) << 5);
      asm volatile("s_waitcnt vmcnt(3)" ::: "memory");
    } else {
      asm volatile("s_waitcnt vmcnt(0)" ::: "memory");
    }
    __builtin_amdgcn_s_barrier();

    const int jj = lane >> 4;
    short8 af[4], bf[2];
#pragma unroll
    for (int mi = 0; mi < 4; mi++) {
      const int r = wr * 64 + mi * 16 + (lane & 15);
      af[mi] = *(const short8*)&As[cur][r * 32 + ((jj ^ ((r >> 1) & 3)) << 3)];
    }
#pragma unroll
    for (int ni = 0; ni < 2; ni++) {
      const int r = wc * 32 + ni * 16 + (lane & 15);
      bf[ni] = *(const short8*)&Bs[cur][r * 32 + ((jj ^ ((r >> 1) & 3)) << 3)];
    }
#pragma unroll
    for (int mi = 0; mi < 4; mi++)
#pragma unroll
      for (int ni = 0; ni < 2; ni++)
        acc[mi][ni] = __builtin_amdgcn_mfma_f32_16x16x32_bf16(af[mi], bf[ni], acc[mi][ni], 0, 0, 0);
    asm volatile("s_waitcnt lgkmcnt(0)" ::: "memory");
    __builtin_amdgcn_s_barrier();
  }

  const int lr = (lane >> 4) * 4;
  const int lc = lane & 15;
#pragma unroll
  for (int mi = 0; mi < 4; mi++) {
#pragma unroll
    for (int ni = 0; ni < 2; ni++) {
      const int col = n0 + wc * 32 + ni * 16 + lc;
      const float bvv = bias[col];
#pragma unroll
      for (int r = 0; r < 4; r++) {
        const int row = m0 + wr * 64 + mi * 16 + lr + r;
        float v = acc[mi][ni][r] + bvv;
        if (EPI == 1) v = fmaxf(v, 0.f);
        C[(long)row * N + col] = f2bf(v);
      }
    }
  }
}

// ---- attention: int8 q,k scores (sdot4, uint4 loads), uint8 v PV ----------
__global__ __launch_bounds__(256, 8) void k_attn(const signed char* __restrict__ qk8,
                                                 const unsigned char* __restrict__ v8,
                                                 const float* __restrict__ maskb,
                                                 const int* __restrict__ inxs,
                                                 unsigned short* __restrict__ att) {
  const int t = threadIdx.x;
  const int lane = t & 63;
  const int w = t >> 6;
  const int bid = blockIdx.x;
  const int xcd = bid & 7;
  const int b = xcd >> 1;
  const int sub = ((bid >> 3) << 1) | (xcd & 1);
  const int row = (b << 11) | (sub << 2) | w;
  const long base = (long)b * 2048;
  const int g = lane >> 4;
  const int li = lane & 15;
  const int kk = lane & 31;

  const int* ix = inxs + (long)row * 32;
  const int ixv = ix[kk];
  const float mval = maskb[(long)row * 32 + kk];

  // q row = 512B = 32 uint4 chunks; lane li covers {li, li+16}
  const uint4* qp = (const uint4*)(qk8 + (long)row * 1024);
  uint4 qc[2];
#pragma unroll
  for (int c = 0; c < 2; c++) qc[c] = qp[li + c * 16];

  // scores: 8 rounds x 4 concurrent neighbors; 2 uint4 loads + 8 sdot4/round
  float scr[8];
#pragma unroll
  for (int r = 0; r < 8; r++) {
    const int nb = __shfl(ixv, r * 4 + g, 64);
    const uint4* kp = (const uint4*)(qk8 + (base + nb) * 1024 + 512);
    int di = 0;
#pragma unroll
    for (int c = 0; c < 2; c++) {
      const uint4 kc = kp[li + c * 16];
      di = __builtin_amdgcn_sdot4((int)kc.x, (int)qc[c].x, di, false);
      di = __builtin_amdgcn_sdot4((int)kc.y, (int)qc[c].y, di, false);
      di = __builtin_amdgcn_sdot4((int)kc.z, (int)qc[c].z, di, false);
      di = __builtin_amdgcn_sdot4((int)kc.w, (int)qc[c].w, di, false);
    }
#pragma unroll
    for (int m = 1; m <= 8; m <<= 1) di += __shfl_xor(di, m, 64);
    scr[r] = (float)di;
  }

  // redistribute: lane kk takes scr[kk>>2] from lane (kk&3)*16
  const int srcl = (kk & 3) << 4;
  float s = __shfl(scr[0], srcl, 64);
#pragma unroll
  for (int r = 1; r < 8; r++) {
    const float tr = __shfl(scr[r], srcl, 64);
    s = ((kk >> 2) == r) ? tr : s;
  }
  s = s * SCONST + mval;

  // softmax across 32 owned scores
  float mx = s;
#pragma unroll
  for (int d = 1; d <= 16; d <<= 1) mx = fmaxf(mx, __shfl_xor(mx, d, 64));
  const float e = __expf(s - mx);
  float ts = e;
#pragma unroll
  for (int d = 1; d <= 16; d <<= 1) ts += __shfl_xor(ts, d, 64);
  const float inv = 1.f / ts;

  // PV: 32 neighbors, uint8 v rows (8 B/lane), byte-extract unpack.
  // v ≈ VSCALE*(u8 - 128): out_j = VSCALE*((Σ e u8_j)/Σe - 128)
  float o[8] = {0, 0, 0, 0, 0, 0, 0, 0};
#pragma unroll
  for (int p = 0; p < 32; p++) {
    const int un = __shfl(ixv, p, 64);
    const float wn = __shfl(e, p, 64);
    const uint2 vv = *(const uint2*)(v8 + (base + un) * 512 + lane * 8);
    o[0] += wn * ub(vv.x, 0);
    o[1] += wn * ub(vv.x, 1);
    o[2] += wn * ub(vv.x, 2);
    o[3] += wn * ub(vv.x, 3);
    o[4] += wn * ub(vv.y, 0);
    o[5] += wn * ub(vv.y, 1);
    o[6] += wn * ub(vv.y, 2);
    o[7] += wn * ub(vv.y, 3);
  }

  short8 ov;
#pragma unroll
  for (int j = 0; j < 8; j++)
    ov[j] = (short)f2bf(VSCALE * (o[j] * inv - 128.f));
  *(short8*)(att + (long)row * 512 + lane * 8) = ov;
}

// ---------------- LN1: y = LN(x_f32 + o_bf16) * g + beta, out bf16 --------
__global__ __launch_bounds__(256) void k_ln1(const float* __restrict__ x,
                                             const unsigned short* __restrict__ o,
                                             const float* __restrict__ g,
                                             const float* __restrict__ beta,
                                             unsigned short* __restrict__ y) {
  const int lane = threadIdx.x & 63;
  const int w = threadIdx.x >> 6;
  const int bid = blockIdx.x;
  const int xcd = bid & 7;
  const int bb = xcd >> 1;
  const int s0 = ((bid >> 3) << 1) | (xcd & 1);
  const long row = ((long)bb << 11) | ((long)s0 << 2) | w;
  const float4* xp = (const float4*)(x + row * 512 + lane * 8);
  float4 x0 = xp[0], x1 = xp[1];
  short8 ov = *(const short8*)(o + row * 512 + lane * 8);
  float tv[8] = {x0.x, x0.y, x0.z, x0.w, x1.x, x1.y, x1.z, x1.w};
  float s = 0.f, s2 = 0.f;
#pragma unroll
  for (int j = 0; j < 8; j++) {
    tv[j] += bf2f((unsigned short)ov[j]);
    s += tv[j];
    s2 += tv[j] * tv[j];
  }
#pragma unroll
  for (int m = 32; m >= 1; m >>= 1) {
    s += __shfl_xor(s, m, 64);
    s2 += __shfl_xor(s2, m, 64);
  }
  const float mean = s * (1.f / 512.f);
  const float var = s2 * (1.f / 512.f) - mean * mean;
  const float r = rsqrtf(var + 1e-5f);
  const float4* gp = (const float4*)(g + lane * 8);
  const float4* bp = (const float4*)(beta + lane * 8);
  float4 g0 = gp[0], g1v = gp[1], b0 = bp[0], b1 = bp[1];
  float gg[8] = {g0.x, g0.y, g0.z, g0.w, g1v.x, g1v.y, g1v.z, g1v.w};
  float bb2[8] = {b0.x, b0.y, b0.z, b0.w, b1.x, b1.y, b1.z, b1.w};
  short8 yv;
#pragma unroll
  for (int j = 0; j < 8; j++) yv[j] = (short)f2bf((tv[j] - mean) * r * gg[j] + bb2[j]);
  *(short8*)(y + row * 512 + lane * 8) = yv;
}

// ---------------- LN2: out_f32 = LN(y_bf16 + f_bf16) * g + beta -----------
__global__ __launch_bounds__(256) void k_ln2(const unsigned short* __restrict__ y,
                                             const unsigned short* __restrict__ f,
                                             const float* __restrict__ g,
                                             const float* __restrict__ beta,
                                             float* __restrict__ out) {
  const int lane = threadIdx.x & 63;
  const int w = threadIdx.x >> 6;
  const int bid = blockIdx.x;
  const int xcd = bid & 7;
  const int bb = xcd >> 1;
  const int s0 = ((bid >> 3) << 1) | (xcd & 1);
  const long row = ((long)bb << 11) | ((long)s0 << 2) | w;
  short8 yv = *(const short8*)(y + row * 512 + lane * 8);
  short8 fv = *(const short8*)(f + row * 512 + lane * 8);
  float tv[8];
  float s = 0.f, s2 = 0.f;
#pragma unroll
  for (int j = 0; j < 8; j++) {
    tv[j] = bf2f((unsigned short)yv[j]) + bf2f((unsigned short)fv[j]);
    s += tv[j];
    s2 += tv[j] * tv[j];
  }
#pragma unroll
  for (int m = 32; m >= 1; m >>= 1) {
    s += __shfl_xor(s, m, 64);
    s2 += __shfl_xor(s2, m, 64);
  }
  const float mean = s * (1.f / 512.f);
  const float var = s2 * (1.f / 512.f) - mean * mean;
  const float r = rsqrtf(var + 1e-5f);
  const float4* gp = (const float4*)(g + lane * 8);
  const float4* bp = (const float4*)(beta + lane * 8);
  float4 g0 = gp[0], g1v = gp[1], b0 = bp[0], b1 = bp[1];
  float gg[8] = {g0.x, g0.y, g0.z, g0.w, g1v.x, g1v.y, g1v.z, g1v.w};
  float bb2[8] = {b0.x, b0.y, b0.z, b0.w, b1.x, b1.y, b1.z, b1.w};
  float ovv[8];
#pragma unroll
  for (int j = 0; j < 8; j++) ovv[j] = (tv[j] - mean) * r * gg[j] + bb2[j];
  float4* op = (float4*)(out + row * 512 + lane * 8);
  float4 o0 = {ovv[0], ovv[1], ovv[2], ovv[3]};
  float4 o1 = {ovv[4], ovv[5], ovv[6], ovv[7]};
  op[0] = o0;
  op[1] = o1;
}

extern "C" void kernel_launch(void* const* d_in, const int* in_sizes, int n_in,
                              void* d_out, int out_size, void* d_ws, size_t ws_size,
                              hipStream_t stream) {
  const float* x   = (const float*)d_in[0];
  const float* adj = (const float*)d_in[1];
  const int*   inx = (const int*)d_in[2];
  const float* Wq  = (const float*)d_in[3];
  const float* bq  = (const float*)d_in[4];
  const float* Wk  = (const float*)d_in[5];
  const float* bk  = (const float*)d_in[6];
  const float* Wv  = (const float*)d_in[7];
  const float* bv  = (const float*)d_in[8];
  const float* Wo  = (const float*)d_in[9];
  const float* bo  = (const float*)d_in[10];
  const float* g1  = (const float*)d_in[11];
  const float* be1 = (const float*)d_in[12];
  const float* W1  = (const float*)d_in[13];
  const float* bf1 = (const float*)d_in[14];
  const float* W2  = (const float*)d_in[15];
  const float* bf2 = (const float*)d_in[16];
  const float* g2  = (const float*)d_in[17];
  const float* be2 = (const float*)d_in[18];

  // workspace (short units). Aliases (stream-ordered safe):
  // att<-xb (dead after G1x); h<-qk8+v8 (12,582,912 B == 8192*768*2 B exactly;
  // both dead after attn); f<-oproj (dead after LN1).
  unsigned short* xb    = (unsigned short*)d_ws;            // 4194304 (x f16)
  unsigned short* wqkvt = xb + 4194304;                     // 786432
  unsigned short* wot   = wqkvt + 786432;                   // 262144
  unsigned short* w1t   = wot + 262144;                     // 393216
  unsigned short* w2t   = w1t + 393216;                     // 393216
  signed char*    qk8   = (signed char*)(w2t + 393216);     // 8 MB
  unsigned char*  v8    = (unsigned char*)(qk8 + 8388608);  // 4 MB
  unsigned short* oproj = (unsigned short*)(v8 + 4194304);  // 4194304
  unsigned short* y     = oproj + 4194304;                  // 4194304
  float*          maskb = (float*)(y + 4194304);            // 1 MB
  unsigned short* att   = xb;
  unsigned short* h     = (unsigned short*)qk8;             // exactly fits
  unsigned short* f     = oproj;

  // prep: x->f16 + Wq/Wk/Wv transposes (only what G1x needs)
  k_prep<<<2816, 256, 0, stream>>>(x, xb, Wq, Wk, Wv, wqkvt);
  // G1x: qkv GEMM + (overlapped) adj-mask gather + Wo/W1/W2 transposes
  k_g1x<<<2816, 256, 0, stream>>>(xb, wqkvt, bq, bk, bv, qk8, v8,
                                  adj, inx, maskb, Wo, W1, W2, wot, w1t, w2t);
  // attention
  k_attn<<<2048, 256, 0, stream>>>(qk8, v8, maskb, inx, att);
  // G2: oproj = relu(att @ Wo + bo)
  k_gemm<1><<<512, 256, 0, stream>>>(att, wot, bo, oproj, 8192, 512, 512);
  // y = LN(x + oproj)
  k_ln1<<<2048, 256, 0, stream>>>(x, oproj, g1, be1, y);
  // G3: h = relu(y @ W1 + bf1)
  k_gemm<1><<<768, 256, 0, stream>>>(y, w1t, bf1, h, 8192, 768, 512);
  // G4: f = h @ W2 + bf2
  k_gemm<0><<<512, 256, 0, stream>>>(h, w2t, bf2, f, 8192, 512, 768);
  // out = LN(y + f)
  k_ln2<<<2048, 256, 0, stream>>>(y, f, g2, be2, (float*)d_out);
}

// Round 15
// 100.265 us; speedup vs baseline: 1.0930x; 1.0930x over previous
//
#include <hip/hip_runtime.h>
#include <stdint.h>

typedef __attribute__((ext_vector_type(8))) short short8;
typedef __attribute__((ext_vector_type(4))) float f32x4;
typedef __attribute__((ext_vector_type(8))) _Float16 half8;

#define QSCALE 21.1666667f    /* 127/6 : q,k,v quantize */
#define VSCALE 0.04724409449f /* 6/127 : v dequant */
#define SCONST 9.86413e-5f    /* (6/127)^2 / sqrt(512) : score dequant */

static __device__ __forceinline__ unsigned short f2bf(float f) {
  unsigned int u = __float_as_uint(f);
  u += 0x7FFFu + ((u >> 16) & 1u);
  return (unsigned short)(u >> 16);
}
static __device__ __forceinline__ float bf2f(unsigned short h) {
  return __uint_as_float(((unsigned int)h) << 16);
}
static __device__ __forceinline__ unsigned short f2h(float f) {
  _Float16 h = (_Float16)f;
  return __builtin_bit_cast(unsigned short, h);
}
static __device__ __forceinline__ signed char q8(float v) {
  float sv = fminf(fmaxf(v * QSCALE, -127.f), 127.f);
  return (signed char)(int)rintf(sv);
}
static __device__ __forceinline__ unsigned char qu8(float v) {
  return (unsigned char)(int)rintf(fminf(fmaxf(v * QSCALE + 128.f, 0.f), 255.f));
}
// LLVM pattern-matches this to v_cvt_f32_ubyteN
static __device__ __forceinline__ float ub(unsigned int x, int n) {
  return (float)((x >> (8 * n)) & 0xffu);
}

#define GLD16(gp, lp) __builtin_amdgcn_global_load_lds( \
    (__attribute__((address_space(1))) void*)(gp), \
    (__attribute__((address_space(3))) void*)(lp), 16, 0, 0)

// --------- prep: x->f16 (2048) | Wq/Wk/Wv transposes (768) -----------------
__global__ __launch_bounds__(256) void k_prep(
    const float* __restrict__ x, unsigned short* __restrict__ xb,
    const float* __restrict__ Wq, const float* __restrict__ Wk,
    const float* __restrict__ Wv, unsigned short* __restrict__ wqkvt) {
  __shared__ float tile[32][33];
  const int bid = blockIdx.x;
  const int t = threadIdx.x;
  if (bid < 2048) {
    const int xcd = bid & 7;
    const int bb = xcd >> 1;
    const int s = ((bid >> 3) << 1) | (xcd & 1);
    const long row = ((long)bb << 11) | ((long)s << 2) | (t >> 6);
    const int lane = t & 63;
    const float4* p = (const float4*)(x + row * 512 + lane * 8);
    float4 a = p[0], b = p[1];
    short8 v;
    v[0] = (short)f2h(a.x); v[1] = (short)f2h(a.y);
    v[2] = (short)f2h(a.z); v[3] = (short)f2h(a.w);
    v[4] = (short)f2h(b.x); v[5] = (short)f2h(b.y);
    v[6] = (short)f2h(b.z); v[7] = (short)f2h(b.w);
    *(short8*)(xb + row * 512 + lane * 8) = v;
    return;
  }
  const int lb = bid - 2048;       // 0..767
  const int m = lb >> 8;           // 0,1,2 -> Wq,Wk,Wv
  const float* src = m == 0 ? Wq : (m == 1 ? Wk : Wv);
  unsigned short* dst = wqkvt + (long)m * 512 * 512;
  const int local = lb & 255;
  const int c0 = (local & 15) << 5;
  const int r0 = (local >> 4) << 5;
  const int tx = t & 31, ty = t >> 5;
#pragma unroll
  for (int i = 0; i < 4; i++)
    tile[ty + i * 8][tx] = src[(long)(r0 + ty + i * 8) * 512 + c0 + tx];
  __syncthreads();
#pragma unroll
  for (int i = 0; i < 4; i++)
    dst[(long)(c0 + ty + i * 8) * 512 + r0 + tx] = f2h(tile[tx][ty + i * 8]);
}

// -- G1x: qkv GEMM 128x64/BK=64 (1536) | adj-mask (1024) | W transposes (1024)
// GEMM matches the proven k_gemm structure (2x the blocks of the 128x128
// version; short-K GEMMs here are block-parallelism-bound, not LDS-bound).
__global__ __launch_bounds__(256) void k_g1x(
    const unsigned short* __restrict__ A, const unsigned short* __restrict__ Bt,
    const float* __restrict__ bq, const float* __restrict__ bk,
    const float* __restrict__ bv, signed char* __restrict__ qk8,
    unsigned char* __restrict__ v8,
    const float* __restrict__ adj, const int* __restrict__ inxs,
    float* __restrict__ maskb,
    const float* __restrict__ Wo, const float* __restrict__ W1,
    const float* __restrict__ W2, unsigned short* __restrict__ wot,
    unsigned short* __restrict__ w1t, unsigned short* __restrict__ w2t) {
  const int K = 512;
  __shared__ unsigned short As[2][128 * 64];
  __shared__ unsigned short Bs[2][64 * 64];
  const int t = threadIdx.x;
  const int bid = blockIdx.x;

  if (bid >= 1536) {
    const int eb = bid - 1536;
    if (eb < 1024) {
      // adj-mask gather: 8 rows/block, one lane per (row,kk)
      const int xcd = eb & 7;
      const int bb = xcd >> 1;
      const int s = ((eb >> 3) << 1) | (xcd & 1);
      const long row = ((long)bb << 11) | ((long)s << 3) | (t >> 5);
      const int kk = t & 31;
      const int idx = inxs[row * 32 + kk];
      const float a = adj[row * 2048 + idx];
      maskb[row * 32 + kk] = a > 0.f ? 0.f : -1e22f;
      return;
    }
    // Wo/W1/W2 transpose, fp32 [R][C] -> bf16 [C][R], 32x32 tiles
    float(*tile)[33] = (float(*)[33]) & As[0][0];  // alias gemm LDS
    const int lb = eb - 1024;  // 0..1023
    const float* src;
    unsigned short* dst;
    int R, C, local;
    if (lb < 256) { src = Wo; dst = wot; R = 512; C = 512; local = lb; }
    else if (lb < 640) { src = W1; dst = w1t; R = 512; C = 768; local = lb - 256; }
    else { src = W2; dst = w2t; R = 768; C = 512; local = lb - 640; }
    const int ntx = C >> 5;
    const int c0 = (local % ntx) << 5;
    const int r0 = (local / ntx) << 5;
    const int tx = t & 31, ty = t >> 5;
#pragma unroll
    for (int i = 0; i < 4; i++)
      tile[ty + i * 8][tx] = src[(long)(r0 + ty + i * 8) * C + c0 + tx];
    __syncthreads();
#pragma unroll
    for (int i = 0; i < 4; i++)
      dst[(long)(c0 + ty + i * 8) * R + r0 + tx] = f2bf(tile[tx][ty + i * 8]);
    return;
  }

  // ---------------- GEMM path (bid 0..1535): 128x64 tile, BK=64 -----------
  const int lane = t & 63;
  const int w = t >> 6;
  const int wr = w >> 1, wc = w & 1;
  const int xcd = bid & 7;
  const int bb = xcd >> 1;
  const int s = ((bid >> 3) << 1) | (xcd & 1);  // 0..383
  const int m0 = (bb * 16 + s / 24) * 128;
  const int n0 = (s % 24) * 64;

  f32x4 acc[4][2];
#pragma unroll
  for (int mi = 0; mi < 4; mi++)
#pragma unroll
    for (int ni = 0; ni < 2; ni++) {
      f32x4 z = {0.f, 0.f, 0.f, 0.f};
      acc[mi][ni] = z;
    }

  auto stage = [&](int buf, int k0) {
#pragma unroll
    for (int i = 0; i < 4; i++) {
      const int c = t + i * 256;
      const int r = c >> 3, j = c & 7;
      GLD16(A + (long)(m0 + r) * K + k0 + ((j ^ (r & 7)) << 3), &As[buf][c * 8]);
    }
#pragma unroll
    for (int i = 0; i < 2; i++) {
      const int c = t + i * 256;
      const int r = c >> 3, j = c & 7;
      GLD16(Bt + (long)(n0 + r) * K + k0 + ((j ^ (r & 7)) << 3), &Bs[buf][c * 8]);
    }
  };

  const int nt = K >> 6;  // 8
  stage(0, 0);
  for (int tt = 0; tt < nt; ++tt) {
    const int cur = tt & 1;
    if (tt + 1 < nt) {
      stage(cur ^ 1, (tt + 1) << 6);
      asm volatile("s_waitcnt vmcnt(6)" ::: "memory");
    } else {
      asm volatile("s_waitcnt vmcnt(0)" ::: "memory");
    }
    __builtin_amdgcn_s_barrier();

#pragma unroll
    for (int kk = 0; kk < 2; kk++) {
      short8 af[4], bf[2];
#pragma unroll
      for (int mi = 0; mi < 4; mi++) {
        const int r = wr * 64 + mi * 16 + (lane & 15);
        const int jj = (kk << 2) + (lane >> 4);
        af[mi] = *(const short8*)&As[cur][r * 64 + ((jj ^ (r & 7)) << 3)];
      }
#pragma unroll
      for (int ni = 0; ni < 2; ni++) {
        const int r = wc * 32 + ni * 16 + (lane & 15);
        const int jj = (kk << 2) + (lane >> 4);
        bf[ni] = *(const short8*)&Bs[cur][r * 64 + ((jj ^ (r & 7)) << 3)];
      }
#pragma unroll
      for (int mi = 0; mi < 4; mi++)
#pragma unroll
        for (int ni = 0; ni < 2; ni++)
          acc[mi][ni] = __builtin_amdgcn_mfma_f32_16x16x32_f16(
              __builtin_bit_cast(half8, af[mi]), __builtin_bit_cast(half8, bf[ni]),
              acc[mi][ni], 0, 0, 0);
    }
    asm volatile("s_waitcnt lgkmcnt(0)" ::: "memory");
    __builtin_amdgcn_s_barrier();
  }

  const int lr = (lane >> 4) * 4;
  const int lc = lane & 15;
  if (n0 < 1024) {  // q,k -> int8
#pragma unroll
    for (int mi = 0; mi < 4; mi++) {
#pragma unroll
      for (int ni = 0; ni < 2; ni++) {
        const int col = n0 + wc * 32 + ni * 16 + lc;
        const float bvv = col < 512 ? bq[col] : bk[col - 512];
#pragma unroll
        for (int r = 0; r < 4; r++) {
          const int row = m0 + wr * 64 + mi * 16 + lr + r;
          qk8[(long)row * 1024 + col] = q8(acc[mi][ni][r] + bvv);
        }
      }
    }
  } else {  // v -> uint8 fixed scale, bias 128
#pragma unroll
    for (int mi = 0; mi < 4; mi++) {
#pragma unroll
      for (int ni = 0; ni < 2; ni++) {
        const int col = n0 + wc * 32 + ni * 16 + lc;
        const float bvv = bv[col - 1024];
#pragma unroll
        for (int r = 0; r < 4; r++) {
          const int row = m0 + wr * 64 + mi * 16 + lr + r;
          v8[(long)row * 512 + (col - 1024)] = qu8(acc[mi][ni][r] + bvv);
        }
      }
    }
  }
}

// ------- bf16 MFMA GEMM, 128x64 tile, BK=64, dbuf + counted vmcnt ---------
// (round-12/13 proven config)
template <int EPI>
__global__ __launch_bounds__(256) void k_gemm(const unsigned short* __restrict__ A,
                                              const unsigned short* __restrict__ Bt,
                                              const float* __restrict__ bias,
                                              unsigned short* __restrict__ C,
                                              int M, int N, int K) {
  __shared__ unsigned short As[2][128 * 64];
  __shared__ unsigned short Bs[2][64 * 64];
  const int t = threadIdx.x;
  const int lane = t & 63;
  const int w = t >> 6;
  const int wr = w >> 1, wc = w & 1;
  const int lin = blockIdx.x;
  const int xcd = lin & 7;
  const int bb = xcd >> 1;
  const int nx = N >> 6;
  const int s = ((lin >> 3) << 1) | (xcd & 1);
  const int m0 = (bb * 16 + s / nx) * 128;
  const int n0 = (s % nx) * 64;

  f32x4 acc[4][2];
#pragma unroll
  for (int mi = 0; mi < 4; mi++)
#pragma unroll
    for (int ni = 0; ni < 2; ni++) {
      f32x4 z = {0.f, 0.f, 0.f, 0.f};
      acc[mi][ni] = z;
    }

  auto stage = [&](int buf, int k0) {
#pragma unroll
    for (int i = 0; i < 4; i++) {
      const int c = t + i * 256;
      const int r = c >> 3, j = c & 7;
      GLD16(A + (long)(m0 + r) * K + k0 + ((j ^ (r & 7)) << 3), &As[buf][c * 8]);
    }
#pragma unroll
    for (int i = 0; i < 2; i++) {
      const int c = t + i * 256;
      const int r = c >> 3, j = c & 7;
      GLD16(Bt + (long)(n0 + r) * K + k0 + ((j ^ (r & 7)) << 3), &Bs[buf][c * 8]);
    }
  };

  const int nt = K >> 6;
  stage(0, 0);
  for (int tt = 0; tt < nt; ++tt) {
    const int cur = tt & 1;
    if (tt + 1 < nt) {
      stage(cur ^ 1, (tt + 1) << 6);
      asm volatile("s_waitcnt vmcnt(6)" ::: "memory");
    } else {
      asm volatile("s_waitcnt vmcnt(0)" ::: "memory");
    }
    __builtin_amdgcn_s_barrier();

#pragma unroll
    for (int kk = 0; kk < 2; kk++) {
      short8 af[4], bf[2];
#pragma unroll
      for (int mi = 0; mi < 4; mi++) {
        const int r = wr * 64 + mi * 16 + (lane & 15);
        const int jj = (kk << 2) + (lane >> 4);
        af[mi] = *(const short8*)&As[cur][r * 64 + ((jj ^ (r & 7)) << 3)];
      }
#pragma unroll
      for (int ni = 0; ni < 2; ni++) {
        const int r = wc * 32 + ni * 16 + (lane & 15);
        const int jj = (kk << 2) + (lane >> 4);
        bf[ni] = *(const short8*)&Bs[cur][r * 64 + ((jj ^ (r & 7)) << 3)];
      }
#pragma unroll
      for (int mi = 0; mi < 4; mi++)
#pragma unroll
        for (int ni = 0; ni < 2; ni++)
          acc[mi][ni] = __builtin_amdgcn_mfma_f32_16x16x32_bf16(af[mi], bf[ni], acc[mi][ni], 0, 0, 0);
    }
    asm volatile("s_waitcnt lgkmcnt(0)" ::: "memory");
    __builtin_amdgcn_s_barrier();
  }

  const int lr = (lane >> 4) * 4;
  const int lc = lane & 15;
#pragma unroll
  for (int mi = 0; mi < 4; mi++) {
#pragma unroll
    for (int ni = 0; ni < 2; ni++) {
      const int col = n0 + wc * 32 + ni * 16 + lc;
      const float bvv = bias[col];
#pragma unroll
      for (int r = 0; r < 4; r++) {
        const int row = m0 + wr * 64 + mi * 16 + lr + r;
        float v = acc[mi][ni][r] + bvv;
        if (EPI == 1) v = fmaxf(v, 0.f);
        C[(long)row * N + col] = f2bf(v);
      }
    }
  }
}

// ---- attention: int8 q,k scores (sdot4, uint4 loads), uint8 v PV ----------
__global__ __launch_bounds__(256, 8) void k_attn(const signed char* __restrict__ qk8,
                                                 const unsigned char* __restrict__ v8,
                                                 const float* __restrict__ maskb,
                                                 const int* __restrict__ inxs,
                                                 unsigned short* __restrict__ att) {
  const int t = threadIdx.x;
  const int lane = t & 63;
  const int w = t >> 6;
  const int bid = blockIdx.x;
  const int xcd = bid & 7;
  const int b = xcd >> 1;
  const int sub = ((bid >> 3) << 1) | (xcd & 1);
  const int row = (b << 11) | (sub << 2) | w;
  const long base = (long)b * 2048;
  const int g = lane >> 4;
  const int li = lane & 15;
  const int kk = lane & 31;

  const int* ix = inxs + (long)row * 32;
  const int ixv = ix[kk];
  const float mval = maskb[(long)row * 32 + kk];

  // q row = 512B = 32 uint4 chunks; lane li covers {li, li+16}
  const uint4* qp = (const uint4*)(qk8 + (long)row * 1024);
  uint4 qc[2];
#pragma unroll
  for (int c = 0; c < 2; c++) qc[c] = qp[li + c * 16];

  // scores: 8 rounds x 4 concurrent neighbors; 2 uint4 loads + 8 sdot4/round
  float scr[8];
#pragma unroll
  for (int r = 0; r < 8; r++) {
    const int nb = __shfl(ixv, r * 4 + g, 64);
    const uint4* kp = (const uint4*)(qk8 + (base + nb) * 1024 + 512);
    int di = 0;
#pragma unroll
    for (int c = 0; c < 2; c++) {
      const uint4 kc = kp[li + c * 16];
      di = __builtin_amdgcn_sdot4((int)kc.x, (int)qc[c].x, di, false);
      di = __builtin_amdgcn_sdot4((int)kc.y, (int)qc[c].y, di, false);
      di = __builtin_amdgcn_sdot4((int)kc.z, (int)qc[c].z, di, false);
      di = __builtin_amdgcn_sdot4((int)kc.w, (int)qc[c].w, di, false);
    }
#pragma unroll
    for (int m = 1; m <= 8; m <<= 1) di += __shfl_xor(di, m, 64);
    scr[r] = (float)di;
  }

  // redistribute: lane kk takes scr[kk>>2] from lane (kk&3)*16
  const int srcl = (kk & 3) << 4;
  float s = __shfl(scr[0], srcl, 64);
#pragma unroll
  for (int r = 1; r < 8; r++) {
    const float tr = __shfl(scr[r], srcl, 64);
    s = ((kk >> 2) == r) ? tr : s;
  }
  s = s * SCONST + mval;

  // softmax across 32 owned scores
  float mx = s;
#pragma unroll
  for (int d = 1; d <= 16; d <<= 1) mx = fmaxf(mx, __shfl_xor(mx, d, 64));
  const float e = __expf(s - mx);
  float ts = e;
#pragma unroll
  for (int d = 1; d <= 16; d <<= 1) ts += __shfl_xor(ts, d, 64);
  const float inv = 1.f / ts;

  // PV: 32 neighbors, uint8 v rows (8 B/lane), byte-extract unpack.
  // v ≈ VSCALE*(u8 - 128): out_j = VSCALE*((Σ e u8_j)/Σe - 128)
  float o[8] = {0, 0, 0, 0, 0, 0, 0, 0};
#pragma unroll
  for (int p = 0; p < 32; p++) {
    const int un = __shfl(ixv, p, 64);
    const float wn = __shfl(e, p, 64);
    const uint2 vv = *(const uint2*)(v8 + (base + un) * 512 + lane * 8);
    o[0] += wn * ub(vv.x, 0);
    o[1] += wn * ub(vv.x, 1);
    o[2] += wn * ub(vv.x, 2);
    o[3] += wn * ub(vv.x, 3);
    o[4] += wn * ub(vv.y, 0);
    o[5] += wn * ub(vv.y, 1);
    o[6] += wn * ub(vv.y, 2);
    o[7] += wn * ub(vv.y, 3);
  }

  short8 ov;
#pragma unroll
  for (int j = 0; j < 8; j++)
    ov[j] = (short)f2bf(VSCALE * (o[j] * inv - 128.f));
  *(short8*)(att + (long)row * 512 + lane * 8) = ov;
}

// ---------------- LN1: y = LN(x_f32 + o_bf16) * g + beta, out bf16 --------
__global__ __launch_bounds__(256) void k_ln1(const float* __restrict__ x,
                                             const unsigned short* __restrict__ o,
                                             const float* __restrict__ g,
                                             const float* __restrict__ beta,
                                             unsigned short* __restrict__ y) {
  const int lane = threadIdx.x & 63;
  const int w = threadIdx.x >> 6;
  const int bid = blockIdx.x;
  const int xcd = bid & 7;
  const int bb = xcd >> 1;
  const int s0 = ((bid >> 3) << 1) | (xcd & 1);
  const long row = ((long)bb << 11) | ((long)s0 << 2) | w;
  const float4* xp = (const float4*)(x + row * 512 + lane * 8);
  float4 x0 = xp[0], x1 = xp[1];
  short8 ov = *(const short8*)(o + row * 512 + lane * 8);
  float tv[8] = {x0.x, x0.y, x0.z, x0.w, x1.x, x1.y, x1.z, x1.w};
  float s = 0.f, s2 = 0.f;
#pragma unroll
  for (int j = 0; j < 8; j++) {
    tv[j] += bf2f((unsigned short)ov[j]);
    s += tv[j];
    s2 += tv[j] * tv[j];
  }
#pragma unroll
  for (int m = 32; m >= 1; m >>= 1) {
    s += __shfl_xor(s, m, 64);
    s2 += __shfl_xor(s2, m, 64);
  }
  const float mean = s * (1.f / 512.f);
  const float var = s2 * (1.f / 512.f) - mean * mean;
  const float r = rsqrtf(var + 1e-5f);
  const float4* gp = (const float4*)(g + lane * 8);
  const float4* bp = (const float4*)(beta + lane * 8);
  float4 g0 = gp[0], g1v = gp[1], b0 = bp[0], b1 = bp[1];
  float gg[8] = {g0.x, g0.y, g0.z, g0.w, g1v.x, g1v.y, g1v.z, g1v.w};
  float bb2[8] = {b0.x, b0.y, b0.z, b0.w, b1.x, b1.y, b1.z, b1.w};
  short8 yv;
#pragma unroll
  for (int j = 0; j < 8; j++) yv[j] = (short)f2bf((tv[j] - mean) * r * gg[j] + bb2[j]);
  *(short8*)(y + row * 512 + lane * 8) = yv;
}

// ---------------- LN2: out_f32 = LN(y_bf16 + f_bf16) * g + beta -----------
__global__ __launch_bounds__(256) void k_ln2(const unsigned short* __restrict__ y,
                                             const unsigned short* __restrict__ f,
                                             const float* __restrict__ g,
                                             const float* __restrict__ beta,
                                             float* __restrict__ out) {
  const int lane = threadIdx.x & 63;
  const int w = threadIdx.x >> 6;
  const int bid = blockIdx.x;
  const int xcd = bid & 7;
  const int bb = xcd >> 1;
  const int s0 = ((bid >> 3) << 1) | (xcd & 1);
  const long row = ((long)bb << 11) | ((long)s0 << 2) | w;
  short8 yv = *(const short8*)(y + row * 512 + lane * 8);
  short8 fv = *(const short8*)(f + row * 512 + lane * 8);
  float tv[8];
  float s = 0.f, s2 = 0.f;
#pragma unroll
  for (int j = 0; j < 8; j++) {
    tv[j] = bf2f((unsigned short)yv[j]) + bf2f((unsigned short)fv[j]);
    s += tv[j];
    s2 += tv[j] * tv[j];
  }
#pragma unroll
  for (int m = 32; m >= 1; m >>= 1) {
    s += __shfl_xor(s, m, 64);
    s2 += __shfl_xor(s2, m, 64);
  }
  const float mean = s * (1.f / 512.f);
  const float var = s2 * (1.f / 512.f) - mean * mean;
  const float r = rsqrtf(var + 1e-5f);
  const float4* gp = (const float4*)(g + lane * 8);
  const float4* bp = (const float4*)(beta + lane * 8);
  float4 g0 = gp[0], g1v = gp[1], b0 = bp[0], b1 = bp[1];
  float gg[8] = {g0.x, g0.y, g0.z, g0.w, g1v.x, g1v.y, g1v.z, g1v.w};
  float bb2[8] = {b0.x, b0.y, b0.z, b0.w, b1.x, b1.y, b1.z, b1.w};
  float ovv[8];
#pragma unroll
  for (int j = 0; j < 8; j++) ovv[j] = (tv[j] - mean) * r * gg[j] + bb2[j];
  float4* op = (float4*)(out + row * 512 + lane * 8);
  float4 o0 = {ovv[0], ovv[1], ovv[2], ovv[3]};
  float4 o1 = {ovv[4], ovv[5], ovv[6], ovv[7]};
  op[0] = o0;
  op[1] = o1;
}

extern "C" void kernel_launch(void* const* d_in, const int* in_sizes, int n_in,
                              void* d_out, int out_size, void* d_ws, size_t ws_size,
                              hipStream_t stream) {
  const float* x   = (const float*)d_in[0];
  const float* adj = (const float*)d_in[1];
  const int*   inx = (const int*)d_in[2];
  const float* Wq  = (const float*)d_in[3];
  const float* bq  = (const float*)d_in[4];
  const float* Wk  = (const float*)d_in[5];
  const float* bk  = (const float*)d_in[6];
  const float* Wv  = (const float*)d_in[7];
  const float* bv  = (const float*)d_in[8];
  const float* Wo  = (const float*)d_in[9];
  const float* bo  = (const float*)d_in[10];
  const float* g1  = (const float*)d_in[11];
  const float* be1 = (const float*)d_in[12];
  const float* W1  = (const float*)d_in[13];
  const float* bf1 = (const float*)d_in[14];
  const float* W2  = (const float*)d_in[15];
  const float* bf2 = (const float*)d_in[16];
  const float* g2  = (const float*)d_in[17];
  const float* be2 = (const float*)d_in[18];

  // workspace (short units). Aliases (stream-ordered safe):
  // att<-xb (dead after G1x); h<-qk8+v8 (12,582,912 B == 8192*768*2 B exactly;
  // both dead after attn); f<-oproj (dead after LN1).
  unsigned short* xb    = (unsigned short*)d_ws;            // 4194304 (x f16)
  unsigned short* wqkvt = xb + 4194304;                     // 786432
  unsigned short* wot   = wqkvt + 786432;                   // 262144
  unsigned short* w1t   = wot + 262144;                     // 393216
  unsigned short* w2t   = w1t + 393216;                     // 393216
  signed char*    qk8   = (signed char*)(w2t + 393216);     // 8 MB
  unsigned char*  v8    = (unsigned char*)(qk8 + 8388608);  // 4 MB
  unsigned short* oproj = (unsigned short*)(v8 + 4194304);  // 4194304
  unsigned short* y     = oproj + 4194304;                  // 4194304
  float*          maskb = (float*)(y + 4194304);            // 1 MB
  unsigned short* att   = xb;
  unsigned short* h     = (unsigned short*)qk8;             // exactly fits
  unsigned short* f     = oproj;

  // prep: x->f16 + Wq/Wk/Wv transposes (only what G1x needs)
  k_prep<<<2816, 256, 0, stream>>>(x, xb, Wq, Wk, Wv, wqkvt);
  // G1x: qkv GEMM (1536 blocks, 128x64) + adj-mask + Wo/W1/W2 transposes
  k_g1x<<<3584, 256, 0, stream>>>(xb, wqkvt, bq, bk, bv, qk8, v8,
                                  adj, inx, maskb, Wo, W1, W2, wot, w1t, w2t);
  // attention
  k_attn<<<2048, 256, 0, stream>>>(qk8, v8, maskb, inx, att);
  // G2: oproj = relu(att @ Wo + bo)
  k_gemm<1><<<512, 256, 0, stream>>>(att, wot, bo, oproj, 8192, 512, 512);
  // y = LN(x + oproj)
  k_ln1<<<2048, 256, 0, stream>>>(x, oproj, g1, be1, y);
  // G3: h = relu(y @ W1 + bf1)
  k_gemm<1><<<768, 256, 0, stream>>>(y, w1t, bf1, h, 8192, 768, 512);
  // G4: f = h @ W2 + bf2
  k_gemm<0><<<512, 256, 0, stream>>>(h, w2t, bf2, f, 8192, 512, 768);
  // out = LN(y + f)
  k_ln2<<<2048, 256, 0, stream>>>(y, f, g2, be2, (float*)d_out);
}

// Round 16
// 99.091 us; speedup vs baseline: 1.1059x; 1.0118x over previous
//
#include <hip/hip_runtime.h>
#include <stdint.h>

typedef __attribute__((ext_vector_type(8))) short short8;
typedef __attribute__((ext_vector_type(4))) float f32x4;
typedef __attribute__((ext_vector_type(8))) _Float16 half8;

#define QSCALE 21.1666667f    /* 127/6 : q,k,v quantize */
#define VSCALE 0.04724409449f /* 6/127 : v dequant */
#define SCONST 9.86413e-5f    /* (6/127)^2 / sqrt(512) : score dequant */

static __device__ __forceinline__ unsigned short f2bf(float f) {
  unsigned int u = __float_as_uint(f);
  u += 0x7FFFu + ((u >> 16) & 1u);
  return (unsigned short)(u >> 16);
}
static __device__ __forceinline__ float bf2f(unsigned short h) {
  return __uint_as_float(((unsigned int)h) << 16);
}
static __device__ __forceinline__ unsigned short f2h(float f) {
  _Float16 h = (_Float16)f;
  return __builtin_bit_cast(unsigned short, h);
}
static __device__ __forceinline__ float h2f(unsigned short h) {
  return (float)__builtin_bit_cast(_Float16, h);
}
static __device__ __forceinline__ signed char q8(float v) {
  float sv = fminf(fmaxf(v * QSCALE, -127.f), 127.f);
  return (signed char)(int)rintf(sv);
}
static __device__ __forceinline__ unsigned char qu8(float v) {
  return (unsigned char)(int)rintf(fminf(fmaxf(v * QSCALE + 128.f, 0.f), 255.f));
}
// LLVM pattern-matches this to v_cvt_f32_ubyteN
static __device__ __forceinline__ float ub(unsigned int x, int n) {
  return (float)((x >> (8 * n)) & 0xffu);
}

#define GLD16(gp, lp) __builtin_amdgcn_global_load_lds( \
    (__attribute__((address_space(1))) void*)(gp), \
    (__attribute__((address_space(3))) void*)(lp), 16, 0, 0)

// --------- prep: x->f16 (2048) | Wq/Wk/Wv transposes (768) -----------------
__global__ __launch_bounds__(256) void k_prep(
    const float* __restrict__ x, unsigned short* __restrict__ xb,
    const float* __restrict__ Wq, const float* __restrict__ Wk,
    const float* __restrict__ Wv, unsigned short* __restrict__ wqkvt) {
  __shared__ float tile[32][33];
  const int bid = blockIdx.x;
  const int t = threadIdx.x;
  if (bid < 2048) {
    const int xcd = bid & 7;
    const int bb = xcd >> 1;
    const int s = ((bid >> 3) << 1) | (xcd & 1);
    const long row = ((long)bb << 11) | ((long)s << 2) | (t >> 6);
    const int lane = t & 63;
    const float4* p = (const float4*)(x + row * 512 + lane * 8);
    float4 a = p[0], b = p[1];
    short8 v;
    v[0] = (short)f2h(a.x); v[1] = (short)f2h(a.y);
    v[2] = (short)f2h(a.z); v[3] = (short)f2h(a.w);
    v[4] = (short)f2h(b.x); v[5] = (short)f2h(b.y);
    v[6] = (short)f2h(b.z); v[7] = (short)f2h(b.w);
    *(short8*)(xb + row * 512 + lane * 8) = v;
    return;
  }
  const int lb = bid - 2048;       // 0..767
  const int m = lb >> 8;           // 0,1,2 -> Wq,Wk,Wv
  const float* src = m == 0 ? Wq : (m == 1 ? Wk : Wv);
  unsigned short* dst = wqkvt + (long)m * 512 * 512;
  const int local = lb & 255;
  const int c0 = (local & 15) << 5;
  const int r0 = (local >> 4) << 5;
  const int tx = t & 31, ty = t >> 5;
#pragma unroll
  for (int i = 0; i < 4; i++)
    tile[ty + i * 8][tx] = src[(long)(r0 + ty + i * 8) * 512 + c0 + tx];
  __syncthreads();
#pragma unroll
  for (int i = 0; i < 4; i++)
    dst[(long)(c0 + ty + i * 8) * 512 + r0 + tx] = f2h(tile[tx][ty + i * 8]);
}

// -- G1x: qkv GEMM 128x64/BK=64 (1536) | adj-mask (1024) | W transposes (1024)
// setprio(1) around the MFMA cluster: g1x has genuine wave-role diversity
// (gather/transpose waves co-resident), the regime where T5 pays (m191).
__global__ __launch_bounds__(256) void k_g1x(
    const unsigned short* __restrict__ A, const unsigned short* __restrict__ Bt,
    const float* __restrict__ bq, const float* __restrict__ bk,
    const float* __restrict__ bv, signed char* __restrict__ qk8,
    unsigned char* __restrict__ v8,
    const float* __restrict__ adj, const int* __restrict__ inxs,
    float* __restrict__ maskb,
    const float* __restrict__ Wo, const float* __restrict__ W1,
    const float* __restrict__ W2, unsigned short* __restrict__ wot,
    unsigned short* __restrict__ w1t, unsigned short* __restrict__ w2t) {
  const int K = 512;
  __shared__ unsigned short As[2][128 * 64];
  __shared__ unsigned short Bs[2][64 * 64];
  const int t = threadIdx.x;
  const int bid = blockIdx.x;

  if (bid >= 1536) {
    const int eb = bid - 1536;
    if (eb < 1024) {
      // adj-mask gather: 8 rows/block, one lane per (row,kk)
      const int xcd = eb & 7;
      const int bb = xcd >> 1;
      const int s = ((eb >> 3) << 1) | (xcd & 1);
      const long row = ((long)bb << 11) | ((long)s << 3) | (t >> 5);
      const int kk = t & 31;
      const int idx = inxs[row * 32 + kk];
      const float a = adj[row * 2048 + idx];
      maskb[row * 32 + kk] = a > 0.f ? 0.f : -1e22f;
      return;
    }
    // Wo/W1/W2 transpose, fp32 [R][C] -> bf16 [C][R], 32x32 tiles
    float(*tile)[33] = (float(*)[33]) & As[0][0];  // alias gemm LDS
    const int lb = eb - 1024;  // 0..1023
    const float* src;
    unsigned short* dst;
    int R, C, local;
    if (lb < 256) { src = Wo; dst = wot; R = 512; C = 512; local = lb; }
    else if (lb < 640) { src = W1; dst = w1t; R = 512; C = 768; local = lb - 256; }
    else { src = W2; dst = w2t; R = 768; C = 512; local = lb - 640; }
    const int ntx = C >> 5;
    const int c0 = (local % ntx) << 5;
    const int r0 = (local / ntx) << 5;
    const int tx = t & 31, ty = t >> 5;
#pragma unroll
    for (int i = 0; i < 4; i++)
      tile[ty + i * 8][tx] = src[(long)(r0 + ty + i * 8) * C + c0 + tx];
    __syncthreads();
#pragma unroll
    for (int i = 0; i < 4; i++)
      dst[(long)(c0 + ty + i * 8) * R + r0 + tx] = f2bf(tile[tx][ty + i * 8]);
    return;
  }

  // ---------------- GEMM path (bid 0..1535): 128x64 tile, BK=64 -----------
  const int lane = t & 63;
  const int w = t >> 6;
  const int wr = w >> 1, wc = w & 1;
  const int xcd = bid & 7;
  const int bb = xcd >> 1;
  const int s = ((bid >> 3) << 1) | (xcd & 1);  // 0..383
  const int m0 = (bb * 16 + s / 24) * 128;
  const int n0 = (s % 24) * 64;

  f32x4 acc[4][2];
#pragma unroll
  for (int mi = 0; mi < 4; mi++)
#pragma unroll
    for (int ni = 0; ni < 2; ni++) {
      f32x4 z = {0.f, 0.f, 0.f, 0.f};
      acc[mi][ni] = z;
    }

  auto stage = [&](int buf, int k0) {
#pragma unroll
    for (int i = 0; i < 4; i++) {
      const int c = t + i * 256;
      const int r = c >> 3, j = c & 7;
      GLD16(A + (long)(m0 + r) * K + k0 + ((j ^ (r & 7)) << 3), &As[buf][c * 8]);
    }
#pragma unroll
    for (int i = 0; i < 2; i++) {
      const int c = t + i * 256;
      const int r = c >> 3, j = c & 7;
      GLD16(Bt + (long)(n0 + r) * K + k0 + ((j ^ (r & 7)) << 3), &Bs[buf][c * 8]);
    }
  };

  const int nt = K >> 6;  // 8
  stage(0, 0);
  for (int tt = 0; tt < nt; ++tt) {
    const int cur = tt & 1;
    if (tt + 1 < nt) {
      stage(cur ^ 1, (tt + 1) << 6);
      asm volatile("s_waitcnt vmcnt(6)" ::: "memory");
    } else {
      asm volatile("s_waitcnt vmcnt(0)" ::: "memory");
    }
    __builtin_amdgcn_s_barrier();

    __builtin_amdgcn_s_setprio(1);
#pragma unroll
    for (int kk = 0; kk < 2; kk++) {
      short8 af[4], bf[2];
#pragma unroll
      for (int mi = 0; mi < 4; mi++) {
        const int r = wr * 64 + mi * 16 + (lane & 15);
        const int jj = (kk << 2) + (lane >> 4);
        af[mi] = *(const short8*)&As[cur][r * 64 + ((jj ^ (r & 7)) << 3)];
      }
#pragma unroll
      for (int ni = 0; ni < 2; ni++) {
        const int r = wc * 32 + ni * 16 + (lane & 15);
        const int jj = (kk << 2) + (lane >> 4);
        bf[ni] = *(const short8*)&Bs[cur][r * 64 + ((jj ^ (r & 7)) << 3)];
      }
#pragma unroll
      for (int mi = 0; mi < 4; mi++)
#pragma unroll
        for (int ni = 0; ni < 2; ni++)
          acc[mi][ni] = __builtin_amdgcn_mfma_f32_16x16x32_f16(
              __builtin_bit_cast(half8, af[mi]), __builtin_bit_cast(half8, bf[ni]),
              acc[mi][ni], 0, 0, 0);
    }
    __builtin_amdgcn_s_setprio(0);
    asm volatile("s_waitcnt lgkmcnt(0)" ::: "memory");
    __builtin_amdgcn_s_barrier();
  }

  const int lr = (lane >> 4) * 4;
  const int lc = lane & 15;
  if (n0 < 1024) {  // q,k -> int8
#pragma unroll
    for (int mi = 0; mi < 4; mi++) {
#pragma unroll
      for (int ni = 0; ni < 2; ni++) {
        const int col = n0 + wc * 32 + ni * 16 + lc;
        const float bvv = col < 512 ? bq[col] : bk[col - 512];
#pragma unroll
        for (int r = 0; r < 4; r++) {
          const int row = m0 + wr * 64 + mi * 16 + lr + r;
          qk8[(long)row * 1024 + col] = q8(acc[mi][ni][r] + bvv);
        }
      }
    }
  } else {  // v -> uint8 fixed scale, bias 128
#pragma unroll
    for (int mi = 0; mi < 4; mi++) {
#pragma unroll
      for (int ni = 0; ni < 2; ni++) {
        const int col = n0 + wc * 32 + ni * 16 + lc;
        const float bvv = bv[col - 1024];
#pragma unroll
        for (int r = 0; r < 4; r++) {
          const int row = m0 + wr * 64 + mi * 16 + lr + r;
          v8[(long)row * 512 + (col - 1024)] = qu8(acc[mi][ni][r] + bvv);
        }
      }
    }
  }
}

// ------- bf16 MFMA GEMM, 128x64 tile, BK=64, dbuf + counted vmcnt ---------
template <int EPI>
__global__ __launch_bounds__(256) void k_gemm(const unsigned short* __restrict__ A,
                                              const unsigned short* __restrict__ Bt,
                                              const float* __restrict__ bias,
                                              unsigned short* __restrict__ C,
                                              int M, int N, int K) {
  __shared__ unsigned short As[2][128 * 64];
  __shared__ unsigned short Bs[2][64 * 64];
  const int t = threadIdx.x;
  const int lane = t & 63;
  const int w = t >> 6;
  const int wr = w >> 1, wc = w & 1;
  const int lin = blockIdx.x;
  const int xcd = lin & 7;
  const int bb = xcd >> 1;
  const int nx = N >> 6;
  const int s = ((lin >> 3) << 1) | (xcd & 1);
  const int m0 = (bb * 16 + s / nx) * 128;
  const int n0 = (s % nx) * 64;

  f32x4 acc[4][2];
#pragma unroll
  for (int mi = 0; mi < 4; mi++)
#pragma unroll
    for (int ni = 0; ni < 2; ni++) {
      f32x4 z = {0.f, 0.f, 0.f, 0.f};
      acc[mi][ni] = z;
    }

  auto stage = [&](int buf, int k0) {
#pragma unroll
    for (int i = 0; i < 4; i++) {
      const int c = t + i * 256;
      const int r = c >> 3, j = c & 7;
      GLD16(A + (long)(m0 + r) * K + k0 + ((j ^ (r & 7)) << 3), &As[buf][c * 8]);
    }
#pragma unroll
    for (int i = 0; i < 2; i++) {
      const int c = t + i * 256;
      const int r = c >> 3, j = c & 7;
      GLD16(Bt + (long)(n0 + r) * K + k0 + ((j ^ (r & 7)) << 3), &Bs[buf][c * 8]);
    }
  };

  const int nt = K >> 6;
  stage(0, 0);
  for (int tt = 0; tt < nt; ++tt) {
    const int cur = tt & 1;
    if (tt + 1 < nt) {
      stage(cur ^ 1, (tt + 1) << 6);
      asm volatile("s_waitcnt vmcnt(6)" ::: "memory");
    } else {
      asm volatile("s_waitcnt vmcnt(0)" ::: "memory");
    }
    __builtin_amdgcn_s_barrier();

    __builtin_amdgcn_s_setprio(1);
#pragma unroll
    for (int kk = 0; kk < 2; kk++) {
      short8 af[4], bf[2];
#pragma unroll
      for (int mi = 0; mi < 4; mi++) {
        const int r = wr * 64 + mi * 16 + (lane & 15);
        const int jj = (kk << 2) + (lane >> 4);
        af[mi] = *(const short8*)&As[cur][r * 64 + ((jj ^ (r & 7)) << 3)];
      }
#pragma unroll
      for (int ni = 0; ni < 2; ni++) {
        const int r = wc * 32 + ni * 16 + (lane & 15);
        const int jj = (kk << 2) + (lane >> 4);
        bf[ni] = *(const short8*)&Bs[cur][r * 64 + ((jj ^ (r & 7)) << 3)];
      }
#pragma unroll
      for (int mi = 0; mi < 4; mi++)
#pragma unroll
        for (int ni = 0; ni < 2; ni++)
          acc[mi][ni] = __builtin_amdgcn_mfma_f32_16x16x32_bf16(af[mi], bf[ni], acc[mi][ni], 0, 0, 0);
    }
    __builtin_amdgcn_s_setprio(0);
    asm volatile("s_waitcnt lgkmcnt(0)" ::: "memory");
    __builtin_amdgcn_s_barrier();
  }

  const int lr = (lane >> 4) * 4;
  const int lc = lane & 15;
#pragma unroll
  for (int mi = 0; mi < 4; mi++) {
#pragma unroll
    for (int ni = 0; ni < 2; ni++) {
      const int col = n0 + wc * 32 + ni * 16 + lc;
      const float bvv = bias[col];
#pragma unroll
      for (int r = 0; r < 4; r++) {
        const int row = m0 + wr * 64 + mi * 16 + lr + r;
        float v = acc[mi][ni][r] + bvv;
        if (EPI == 1) v = fmaxf(v, 0.f);
        C[(long)row * N + col] = f2bf(v);
      }
    }
  }
}

// ---- attention: int8 q,k scores (sdot4, uint4 loads), uint8 v PV ----------
__global__ __launch_bounds__(256, 8) void k_attn(const signed char* __restrict__ qk8,
                                                 const unsigned char* __restrict__ v8,
                                                 const float* __restrict__ maskb,
                                                 const int* __restrict__ inxs,
                                                 unsigned short* __restrict__ att) {
  const int t = threadIdx.x;
  const int lane = t & 63;
  const int w = t >> 6;
  const int bid = blockIdx.x;
  const int xcd = bid & 7;
  const int b = xcd >> 1;
  const int sub = ((bid >> 3) << 1) | (xcd & 1);
  const int row = (b << 11) | (sub << 2) | w;
  const long base = (long)b * 2048;
  const int g = lane >> 4;
  const int li = lane & 15;
  const int kk = lane & 31;

  const int* ix = inxs + (long)row * 32;
  const int ixv = ix[kk];
  const float mval = maskb[(long)row * 32 + kk];

  // q row = 512B = 32 uint4 chunks; lane li covers {li, li+16}
  const uint4* qp = (const uint4*)(qk8 + (long)row * 1024);
  uint4 qc[2];
#pragma unroll
  for (int c = 0; c < 2; c++) qc[c] = qp[li + c * 16];

  // scores: 8 rounds x 4 concurrent neighbors; 2 uint4 loads + 8 sdot4/round
  float scr[8];
#pragma unroll
  for (int r = 0; r < 8; r++) {
    const int nb = __shfl(ixv, r * 4 + g, 64);
    const uint4* kp = (const uint4*)(qk8 + (base + nb) * 1024 + 512);
    int di = 0;
#pragma unroll
    for (int c = 0; c < 2; c++) {
      const uint4 kc = kp[li + c * 16];
      di = __builtin_amdgcn_sdot4((int)kc.x, (int)qc[c].x, di, false);
      di = __builtin_amdgcn_sdot4((int)kc.y, (int)qc[c].y, di, false);
      di = __builtin_amdgcn_sdot4((int)kc.z, (int)qc[c].z, di, false);
      di = __builtin_amdgcn_sdot4((int)kc.w, (int)qc[c].w, di, false);
    }
#pragma unroll
    for (int m = 1; m <= 8; m <<= 1) di += __shfl_xor(di, m, 64);
    scr[r] = (float)di;
  }

  // redistribute: lane kk takes scr[kk>>2] from lane (kk&3)*16
  const int srcl = (kk & 3) << 4;
  float s = __shfl(scr[0], srcl, 64);
#pragma unroll
  for (int r = 1; r < 8; r++) {
    const float tr = __shfl(scr[r], srcl, 64);
    s = ((kk >> 2) == r) ? tr : s;
  }
  s = s * SCONST + mval;

  // softmax across 32 owned scores
  float mx = s;
#pragma unroll
  for (int d = 1; d <= 16; d <<= 1) mx = fmaxf(mx, __shfl_xor(mx, d, 64));
  const float e = __expf(s - mx);
  float ts = e;
#pragma unroll
  for (int d = 1; d <= 16; d <<= 1) ts += __shfl_xor(ts, d, 64);
  const float sinv = VSCALE / ts;

  // PV: 32 neighbors, uint8 v rows (8 B/lane), byte-extract unpack.
  // v ≈ VSCALE*(u8 - 128): out_j = VSCALE*((Σ e u8_j)/Σe - 128)
  float o[8] = {0, 0, 0, 0, 0, 0, 0, 0};
#pragma unroll
  for (int p = 0; p < 32; p++) {
    const int un = __shfl(ixv, p, 64);
    const float wn = __shfl(e, p, 64);
    const uint2 vv = *(const uint2*)(v8 + (base + un) * 512 + lane * 8);
    o[0] += wn * ub(vv.x, 0);
    o[1] += wn * ub(vv.x, 1);
    o[2] += wn * ub(vv.x, 2);
    o[3] += wn * ub(vv.x, 3);
    o[4] += wn * ub(vv.y, 0);
    o[5] += wn * ub(vv.y, 1);
    o[6] += wn * ub(vv.y, 2);
    o[7] += wn * ub(vv.y, 3);
  }

  short8 ov;
#pragma unroll
  for (int j = 0; j < 8; j++)
    ov[j] = (short)f2bf(o[j] * sinv - 128.f * VSCALE);
  *(short8*)(att + (long)row * 512 + lane * 8) = ov;
}

// ------- LN1: y = LN(xb_f16 + o_bf16) * g + beta, out bf16 ----------------
// reads xb (f16) instead of x (f32): -8 MB HBM
__global__ __launch_bounds__(256) void k_ln1(const unsigned short* __restrict__ xb,
                                             const unsigned short* __restrict__ o,
                                             const float* __restrict__ g,
                                             const float* __restrict__ beta,
                                             unsigned short* __restrict__ y) {
  const int lane = threadIdx.x & 63;
  const int w = threadIdx.x >> 6;
  const int bid = blockIdx.x;
  const int xcd = bid & 7;
  const int bb = xcd >> 1;
  const int s0 = ((bid >> 3) << 1) | (xcd & 1);
  const long row = ((long)bb << 11) | ((long)s0 << 2) | w;
  short8 xv = *(const short8*)(xb + row * 512 + lane * 8);
  short8 ov = *(const short8*)(o + row * 512 + lane * 8);
  float tv[8];
  float s = 0.f, s2 = 0.f;
#pragma unroll
  for (int j = 0; j < 8; j++) {
    tv[j] = h2f((unsigned short)xv[j]) + bf2f((unsigned short)ov[j]);
    s += tv[j];
    s2 += tv[j] * tv[j];
  }
#pragma unroll
  for (int m = 32; m >= 1; m >>= 1) {
    s += __shfl_xor(s, m, 64);
    s2 += __shfl_xor(s2, m, 64);
  }
  const float mean = s * (1.f / 512.f);
  const float var = s2 * (1.f / 512.f) - mean * mean;
  const float r = rsqrtf(var + 1e-5f);
  const float4* gp = (const float4*)(g + lane * 8);
  const float4* bp = (const float4*)(beta + lane * 8);
  float4 g0 = gp[0], g1v = gp[1], b0 = bp[0], b1 = bp[1];
  float gg[8] = {g0.x, g0.y, g0.z, g0.w, g1v.x, g1v.y, g1v.z, g1v.w};
  float bb2[8] = {b0.x, b0.y, b0.z, b0.w, b1.x, b1.y, b1.z, b1.w};
  short8 yv;
#pragma unroll
  for (int j = 0; j < 8; j++) yv[j] = (short)f2bf((tv[j] - mean) * r * gg[j] + bb2[j]);
  *(short8*)(y + row * 512 + lane * 8) = yv;
}

// ---------------- LN2: out_f32 = LN(y_bf16 + f_bf16) * g + beta -----------
__global__ __launch_bounds__(256) void k_ln2(const unsigned short* __restrict__ y,
                                             const unsigned short* __restrict__ f,
                                             const float* __restrict__ g,
                                             const float* __restrict__ beta,
                                             float* __restrict__ out) {
  const int lane = threadIdx.x & 63;
  const int w = threadIdx.x >> 6;
  const int bid = blockIdx.x;
  const int xcd = bid & 7;
  const int bb = xcd >> 1;
  const int s0 = ((bid >> 3) << 1) | (xcd & 1);
  const long row = ((long)bb << 11) | ((long)s0 << 2) | w;
  short8 yv = *(const short8*)(y + row * 512 + lane * 8);
  short8 fv = *(const short8*)(f + row * 512 + lane * 8);
  float tv[8];
  float s = 0.f, s2 = 0.f;
#pragma unroll
  for (int j = 0; j < 8; j++) {
    tv[j] = bf2f((unsigned short)yv[j]) + bf2f((unsigned short)fv[j]);
    s += tv[j];
    s2 += tv[j] * tv[j];
  }
#pragma unroll
  for (int m = 32; m >= 1; m >>= 1) {
    s += __shfl_xor(s, m, 64);
    s2 += __shfl_xor(s2, m, 64);
  }
  const float mean = s * (1.f / 512.f);
  const float var = s2 * (1.f / 512.f) - mean * mean;
  const float r = rsqrtf(var + 1e-5f);
  const float4* gp = (const float4*)(g + lane * 8);
  const float4* bp = (const float4*)(beta + lane * 8);
  float4 g0 = gp[0], g1v = gp[1], b0 = bp[0], b1 = bp[1];
  float gg[8] = {g0.x, g0.y, g0.z, g0.w, g1v.x, g1v.y, g1v.z, g1v.w};
  float bb2[8] = {b0.x, b0.y, b0.z, b0.w, b1.x, b1.y, b1.z, b1.w};
  float ovv[8];
#pragma unroll
  for (int j = 0; j < 8; j++) ovv[j] = (tv[j] - mean) * r * gg[j] + bb2[j];
  float4* op = (float4*)(out + row * 512 + lane * 8);
  float4 o0 = {ovv[0], ovv[1], ovv[2], ovv[3]};
  float4 o1 = {ovv[4], ovv[5], ovv[6], ovv[7]};
  op[0] = o0;
  op[1] = o1;
}

extern "C" void kernel_launch(void* const* d_in, const int* in_sizes, int n_in,
                              void* d_out, int out_size, void* d_ws, size_t ws_size,
                              hipStream_t stream) {
  const float* x   = (const float*)d_in[0];
  const float* adj = (const float*)d_in[1];
  const int*   inx = (const int*)d_in[2];
  const float* Wq  = (const float*)d_in[3];
  const float* bq  = (const float*)d_in[4];
  const float* Wk  = (const float*)d_in[5];
  const float* bk  = (const float*)d_in[6];
  const float* Wv  = (const float*)d_in[7];
  const float* bv  = (const float*)d_in[8];
  const float* Wo  = (const float*)d_in[9];
  const float* bo  = (const float*)d_in[10];
  const float* g1  = (const float*)d_in[11];
  const float* be1 = (const float*)d_in[12];
  const float* W1  = (const float*)d_in[13];
  const float* bf1 = (const float*)d_in[14];
  const float* W2  = (const float*)d_in[15];
  const float* bf2 = (const float*)d_in[16];
  const float* g2  = (const float*)d_in[17];
  const float* be2 = (const float*)d_in[18];

  // workspace (short units), ~56.5 MB. Aliases (stream-ordered safe):
  // h<-qk8+v8 (both dead after attn); f<-oproj (dead after LN1).
  // xb stays live through LN1 (read there as f16 x).
  unsigned short* xb    = (unsigned short*)d_ws;            // 4194304 (x f16)
  unsigned short* wqkvt = xb + 4194304;                     // 786432
  unsigned short* wot   = wqkvt + 786432;                   // 262144
  unsigned short* w1t   = wot + 262144;                     // 393216
  unsigned short* w2t   = w1t + 393216;                     // 393216
  signed char*    qk8   = (signed char*)(w2t + 393216);     // 8 MB
  unsigned char*  v8    = (unsigned char*)(qk8 + 8388608);  // 4 MB
  unsigned short* oproj = (unsigned short*)(v8 + 4194304);  // 4194304
  unsigned short* y     = oproj + 4194304;                  // 4194304
  float*          maskb = (float*)(y + 4194304);            // 1 MB
  unsigned short* att   = (unsigned short*)(maskb + 262144); // 4194304 (own buf)
  unsigned short* h     = (unsigned short*)qk8;             // exactly fits
  unsigned short* f     = oproj;

  // prep: x->f16 + Wq/Wk/Wv transposes (only what G1x needs)
  k_prep<<<2816, 256, 0, stream>>>(x, xb, Wq, Wk, Wv, wqkvt);
  // G1x: qkv GEMM (1536 blocks, 128x64) + adj-mask + Wo/W1/W2 transposes
  k_g1x<<<3584, 256, 0, stream>>>(xb, wqkvt, bq, bk, bv, qk8, v8,
                                  adj, inx, maskb, Wo, W1, W2, wot, w1t, w2t);
  // attention
  k_attn<<<2048, 256, 0, stream>>>(qk8, v8, maskb, inx, att);
  // G2: oproj = relu(att @ Wo + bo)
  k_gemm<1><<<512, 256, 0, stream>>>(att, wot, bo, oproj, 8192, 512, 512);
  // y = LN(xb + oproj)
  k_ln1<<<2048, 256, 0, stream>>>(xb, oproj, g1, be1, y);
  // G3: h = relu(y @ W1 + bf1)
  k_gemm<1><<<768, 256, 0, stream>>>(y, w1t, bf1, h, 8192, 768, 512);
  // G4: f = h @ W2 + bf2
  k_gemm<0><<<512, 256, 0, stream>>>(h, w2t, bf2, f, 8192, 512, 768);
  // out = LN(y + f)
  k_ln2<<<2048, 256, 0, stream>>>(y, f, g2, be2, (float*)d_out);
}

// Round 17
// 94.666 us; speedup vs baseline: 1.1576x; 1.0467x over previous
//
#include <hip/hip_runtime.h>
#include <stdint.h>

typedef __attribute__((ext_vector_type(8))) short short8;
typedef __attribute__((ext_vector_type(4))) float f32x4;
typedef __attribute__((ext_vector_type(4))) int i32x4;
typedef __attribute__((ext_vector_type(8))) _Float16 half8;

#define QSCALE 21.1666667f    /* 127/6 : q,k,v,h quantize */
#define VSCALE 0.04724409449f /* 6/127 : v dequant */
#define SCONST 9.86413e-5f    /* (6/127)^2 / sqrt(512) : score dequant */
#define QW2 586.589f          /* 127*sqrt(768)/6 : W2 quantize */
#define SCONST4 8.05405e-5f   /* (6/127)*(6/(127*sqrt(768))) : G4 dequant */

static __device__ __forceinline__ unsigned short f2bf(float f) {
  unsigned int u = __float_as_uint(f);
  u += 0x7FFFu + ((u >> 16) & 1u);
  return (unsigned short)(u >> 16);
}
static __device__ __forceinline__ float bf2f(unsigned short h) {
  return __uint_as_float(((unsigned int)h) << 16);
}
static __device__ __forceinline__ unsigned short f2h(float f) {
  _Float16 h = (_Float16)f;
  return __builtin_bit_cast(unsigned short, h);
}
static __device__ __forceinline__ float h2f(unsigned short h) {
  return (float)__builtin_bit_cast(_Float16, h);
}
static __device__ __forceinline__ signed char q8(float v) {
  float sv = fminf(fmaxf(v * QSCALE, -127.f), 127.f);
  return (signed char)(int)rintf(sv);
}
static __device__ __forceinline__ unsigned char qu8(float v) {
  return (unsigned char)(int)rintf(fminf(fmaxf(v * QSCALE + 128.f, 0.f), 255.f));
}
static __device__ __forceinline__ signed char qw2(float v) {
  float sv = fminf(fmaxf(v * QW2, -127.f), 127.f);
  return (signed char)(int)rintf(sv);
}
// LLVM pattern-matches this to v_cvt_f32_ubyteN
static __device__ __forceinline__ float ub(unsigned int x, int n) {
  return (float)((x >> (8 * n)) & 0xffu);
}

#define GLD16(gp, lp) __builtin_amdgcn_global_load_lds( \
    (__attribute__((address_space(1))) void*)(gp), \
    (__attribute__((address_space(3))) void*)(lp), 16, 0, 0)

// --------- prep: x->f16 (2048) | Wq/Wk/Wv transposes (768) -----------------
__global__ __launch_bounds__(256) void k_prep(
    const float* __restrict__ x, unsigned short* __restrict__ xb,
    const float* __restrict__ Wq, const float* __restrict__ Wk,
    const float* __restrict__ Wv, unsigned short* __restrict__ wqkvt) {
  __shared__ float tile[32][33];
  const int bid = blockIdx.x;
  const int t = threadIdx.x;
  if (bid < 2048) {
    const int xcd = bid & 7;
    const int bb = xcd >> 1;
    const int s = ((bid >> 3) << 1) | (xcd & 1);
    const long row = ((long)bb << 11) | ((long)s << 2) | (t >> 6);
    const int lane = t & 63;
    const float4* p = (const float4*)(x + row * 512 + lane * 8);
    float4 a = p[0], b = p[1];
    short8 v;
    v[0] = (short)f2h(a.x); v[1] = (short)f2h(a.y);
    v[2] = (short)f2h(a.z); v[3] = (short)f2h(a.w);
    v[4] = (short)f2h(b.x); v[5] = (short)f2h(b.y);
    v[6] = (short)f2h(b.z); v[7] = (short)f2h(b.w);
    *(short8*)(xb + row * 512 + lane * 8) = v;
    return;
  }
  const int lb = bid - 2048;       // 0..767
  const int m = lb >> 8;           // 0,1,2 -> Wq,Wk,Wv
  const float* src = m == 0 ? Wq : (m == 1 ? Wk : Wv);
  unsigned short* dst = wqkvt + (long)m * 512 * 512;
  const int local = lb & 255;
  const int c0 = (local & 15) << 5;
  const int r0 = (local >> 4) << 5;
  const int tx = t & 31, ty = t >> 5;
#pragma unroll
  for (int i = 0; i < 4; i++)
    tile[ty + i * 8][tx] = src[(long)(r0 + ty + i * 8) * 512 + c0 + tx];
  __syncthreads();
#pragma unroll
  for (int i = 0; i < 4; i++)
    dst[(long)(c0 + ty + i * 8) * 512 + r0 + tx] = f2h(tile[tx][ty + i * 8]);
}

// -- G1x: qkv GEMM 128x64/BK=64 (1536) | adj-mask (1024) | W transposes (1024)
__global__ __launch_bounds__(256) void k_g1x(
    const unsigned short* __restrict__ A, const unsigned short* __restrict__ Bt,
    const float* __restrict__ bq, const float* __restrict__ bk,
    const float* __restrict__ bv, signed char* __restrict__ qk8,
    unsigned char* __restrict__ v8,
    const float* __restrict__ adj, const int* __restrict__ inxs,
    float* __restrict__ maskb,
    const float* __restrict__ Wo, const float* __restrict__ W1,
    const float* __restrict__ W2, unsigned short* __restrict__ wot,
    unsigned short* __restrict__ w1t, signed char* __restrict__ w2t8) {
  const int K = 512;
  __shared__ unsigned short As[2][128 * 64];
  __shared__ unsigned short Bs[2][64 * 64];
  const int t = threadIdx.x;
  const int bid = blockIdx.x;

  if (bid >= 1536) {
    const int eb = bid - 1536;
    if (eb < 1024) {
      // adj-mask gather: 8 rows/block, one lane per (row,kk)
      const int xcd = eb & 7;
      const int bb = xcd >> 1;
      const int s = ((eb >> 3) << 1) | (xcd & 1);
      const long row = ((long)bb << 11) | ((long)s << 3) | (t >> 5);
      const int kk = t & 31;
      const int idx = inxs[row * 32 + kk];
      const float a = adj[row * 2048 + idx];
      maskb[row * 32 + kk] = a > 0.f ? 0.f : -1e22f;
      return;
    }
    // Wo/W1 -> bf16 transpose; W2 -> int8 transpose. 32x32 tiles.
    float(*tile)[33] = (float(*)[33]) & As[0][0];  // alias gemm LDS
    const int lb = eb - 1024;  // 0..1023
    const float* src;
    int R, C, local, w2;
    unsigned short* dst = nullptr;
    if (lb < 256) { src = Wo; dst = wot; R = 512; C = 512; local = lb; w2 = 0; }
    else if (lb < 640) { src = W1; dst = w1t; R = 512; C = 768; local = lb - 256; w2 = 0; }
    else { src = W2; R = 768; C = 512; local = lb - 640; w2 = 1; }
    const int ntx = C >> 5;
    const int c0 = (local % ntx) << 5;
    const int r0 = (local / ntx) << 5;
    const int tx = t & 31, ty = t >> 5;
#pragma unroll
    for (int i = 0; i < 4; i++)
      tile[ty + i * 8][tx] = src[(long)(r0 + ty + i * 8) * C + c0 + tx];
    __syncthreads();
    if (w2) {
#pragma unroll
      for (int i = 0; i < 4; i++)
        w2t8[(long)(c0 + ty + i * 8) * R + r0 + tx] = qw2(tile[tx][ty + i * 8]);
    } else {
#pragma unroll
      for (int i = 0; i < 4; i++)
        dst[(long)(c0 + ty + i * 8) * R + r0 + tx] = f2bf(tile[tx][ty + i * 8]);
    }
    return;
  }

  // ---------------- GEMM path (bid 0..1535): 128x64 tile, BK=64 -----------
  const int lane = t & 63;
  const int w = t >> 6;
  const int wr = w >> 1, wc = w & 1;
  const int xcd = bid & 7;
  const int bb = xcd >> 1;
  const int s = ((bid >> 3) << 1) | (xcd & 1);  // 0..383
  const int m0 = (bb * 16 + s / 24) * 128;
  const int n0 = (s % 24) * 64;

  f32x4 acc[4][2];
#pragma unroll
  for (int mi = 0; mi < 4; mi++)
#pragma unroll
    for (int ni = 0; ni < 2; ni++) {
      f32x4 z = {0.f, 0.f, 0.f, 0.f};
      acc[mi][ni] = z;
    }

  auto stage = [&](int buf, int k0) {
#pragma unroll
    for (int i = 0; i < 4; i++) {
      const int c = t + i * 256;
      const int r = c >> 3, j = c & 7;
      GLD16(A + (long)(m0 + r) * K + k0 + ((j ^ (r & 7)) << 3), &As[buf][c * 8]);
    }
#pragma unroll
    for (int i = 0; i < 2; i++) {
      const int c = t + i * 256;
      const int r = c >> 3, j = c & 7;
      GLD16(Bt + (long)(n0 + r) * K + k0 + ((j ^ (r & 7)) << 3), &Bs[buf][c * 8]);
    }
  };

  const int nt = K >> 6;  // 8
  stage(0, 0);
  for (int tt = 0; tt < nt; ++tt) {
    const int cur = tt & 1;
    if (tt + 1 < nt) {
      stage(cur ^ 1, (tt + 1) << 6);
      asm volatile("s_waitcnt vmcnt(6)" ::: "memory");
    } else {
      asm volatile("s_waitcnt vmcnt(0)" ::: "memory");
    }
    __builtin_amdgcn_s_barrier();

    __builtin_amdgcn_s_setprio(1);
#pragma unroll
    for (int kk = 0; kk < 2; kk++) {
      short8 af[4], bf[2];
#pragma unroll
      for (int mi = 0; mi < 4; mi++) {
        const int r = wr * 64 + mi * 16 + (lane & 15);
        const int jj = (kk << 2) + (lane >> 4);
        af[mi] = *(const short8*)&As[cur][r * 64 + ((jj ^ (r & 7)) << 3)];
      }
#pragma unroll
      for (int ni = 0; ni < 2; ni++) {
        const int r = wc * 32 + ni * 16 + (lane & 15);
        const int jj = (kk << 2) + (lane >> 4);
        bf[ni] = *(const short8*)&Bs[cur][r * 64 + ((jj ^ (r & 7)) << 3)];
      }
#pragma unroll
      for (int mi = 0; mi < 4; mi++)
#pragma unroll
        for (int ni = 0; ni < 2; ni++)
          acc[mi][ni] = __builtin_amdgcn_mfma_f32_16x16x32_f16(
              __builtin_bit_cast(half8, af[mi]), __builtin_bit_cast(half8, bf[ni]),
              acc[mi][ni], 0, 0, 0);
    }
    __builtin_amdgcn_s_setprio(0);
    asm volatile("s_waitcnt lgkmcnt(0)" ::: "memory");
    __builtin_amdgcn_s_barrier();
  }

  const int lr = (lane >> 4) * 4;
  const int lc = lane & 15;
  if (n0 < 1024) {  // q,k -> int8
#pragma unroll
    for (int mi = 0; mi < 4; mi++) {
#pragma unroll
      for (int ni = 0; ni < 2; ni++) {
        const int col = n0 + wc * 32 + ni * 16 + lc;
        const float bvv = col < 512 ? bq[col] : bk[col - 512];
#pragma unroll
        for (int r = 0; r < 4; r++) {
          const int row = m0 + wr * 64 + mi * 16 + lr + r;
          qk8[(long)row * 1024 + col] = q8(acc[mi][ni][r] + bvv);
        }
      }
    }
  } else {  // v -> uint8 fixed scale, bias 128
#pragma unroll
    for (int mi = 0; mi < 4; mi++) {
#pragma unroll
      for (int ni = 0; ni < 2; ni++) {
        const int col = n0 + wc * 32 + ni * 16 + lc;
        const float bvv = bv[col - 1024];
#pragma unroll
        for (int r = 0; r < 4; r++) {
          const int row = m0 + wr * 64 + mi * 16 + lr + r;
          v8[(long)row * 512 + (col - 1024)] = qu8(acc[mi][ni][r] + bvv);
        }
      }
    }
  }
}

// ------- bf16 MFMA GEMM, 128x64 tile, BK=64, dbuf + counted vmcnt ---------
// EPI: 0 = bias, 1 = bias+relu (bf16 out), 2 = bias+relu+int8-quant out.
template <int EPI>
__global__ __launch_bounds__(256) void k_gemm(const unsigned short* __restrict__ A,
                                              const unsigned short* __restrict__ Bt,
                                              const float* __restrict__ bias,
                                              unsigned short* __restrict__ C,
                                              int M, int N, int K) {
  __shared__ unsigned short As[2][128 * 64];
  __shared__ unsigned short Bs[2][64 * 64];
  const int t = threadIdx.x;
  const int lane = t & 63;
  const int w = t >> 6;
  const int wr = w >> 1, wc = w & 1;
  const int lin = blockIdx.x;
  const int xcd = lin & 7;
  const int bb = xcd >> 1;
  const int nx = N >> 6;
  const int s = ((lin >> 3) << 1) | (xcd & 1);
  const int m0 = (bb * 16 + s / nx) * 128;
  const int n0 = (s % nx) * 64;

  f32x4 acc[4][2];
#pragma unroll
  for (int mi = 0; mi < 4; mi++)
#pragma unroll
    for (int ni = 0; ni < 2; ni++) {
      f32x4 z = {0.f, 0.f, 0.f, 0.f};
      acc[mi][ni] = z;
    }

  auto stage = [&](int buf, int k0) {
#pragma unroll
    for (int i = 0; i < 4; i++) {
      const int c = t + i * 256;
      const int r = c >> 3, j = c & 7;
      GLD16(A + (long)(m0 + r) * K + k0 + ((j ^ (r & 7)) << 3), &As[buf][c * 8]);
    }
#pragma unroll
    for (int i = 0; i < 2; i++) {
      const int c = t + i * 256;
      const int r = c >> 3, j = c & 7;
      GLD16(Bt + (long)(n0 + r) * K + k0 + ((j ^ (r & 7)) << 3), &Bs[buf][c * 8]);
    }
  };

  const int nt = K >> 6;
  stage(0, 0);
  for (int tt = 0; tt < nt; ++tt) {
    const int cur = tt & 1;
    if (tt + 1 < nt) {
      stage(cur ^ 1, (tt + 1) << 6);
      asm volatile("s_waitcnt vmcnt(6)" ::: "memory");
    } else {
      asm volatile("s_waitcnt vmcnt(0)" ::: "memory");
    }
    __builtin_amdgcn_s_barrier();

    __builtin_amdgcn_s_setprio(1);
#pragma unroll
    for (int kk = 0; kk < 2; kk++) {
      short8 af[4], bf[2];
#pragma unroll
      for (int mi = 0; mi < 4; mi++) {
        const int r = wr * 64 + mi * 16 + (lane & 15);
        const int jj = (kk << 2) + (lane >> 4);
        af[mi] = *(const short8*)&As[cur][r * 64 + ((jj ^ (r & 7)) << 3)];
      }
#pragma unroll
      for (int ni = 0; ni < 2; ni++) {
        const int r = wc * 32 + ni * 16 + (lane & 15);
        const int jj = (kk << 2) + (lane >> 4);
        bf[ni] = *(const short8*)&Bs[cur][r * 64 + ((jj ^ (r & 7)) << 3)];
      }
#pragma unroll
      for (int mi = 0; mi < 4; mi++)
#pragma unroll
        for (int ni = 0; ni < 2; ni++)
          acc[mi][ni] = __builtin_amdgcn_mfma_f32_16x16x32_bf16(af[mi], bf[ni], acc[mi][ni], 0, 0, 0);
    }
    __builtin_amdgcn_s_setprio(0);
    asm volatile("s_waitcnt lgkmcnt(0)" ::: "memory");
    __builtin_amdgcn_s_barrier();
  }

  const int lr = (lane >> 4) * 4;
  const int lc = lane & 15;
#pragma unroll
  for (int mi = 0; mi < 4; mi++) {
#pragma unroll
    for (int ni = 0; ni < 2; ni++) {
      const int col = n0 + wc * 32 + ni * 16 + lc;
      const float bvv = bias[col];
#pragma unroll
      for (int r = 0; r < 4; r++) {
        const int row = m0 + wr * 64 + mi * 16 + lr + r;
        float v = acc[mi][ni][r] + bvv;
        if (EPI >= 1) v = fmaxf(v, 0.f);
        if (EPI == 2) {
          ((signed char*)C)[(long)row * N + col] =
              (signed char)(int)rintf(fminf(v * QSCALE, 127.f));
        } else {
          C[(long)row * N + col] = f2bf(v);
        }
      }
    }
  }
}

// ------- G4: int8 MFMA GEMM, 128x64 tile, BK=64, dbuf, 24 KB LDS ----------
// f[8192][512] bf16 = (h8[8192][768] @ w2t8[512][768]^T) * SCONST4 + bf2
__global__ __launch_bounds__(256) void k_gemm4(const signed char* __restrict__ A,
                                               const signed char* __restrict__ Bt,
                                               const float* __restrict__ bias,
                                               unsigned short* __restrict__ C) {
  const int K = 768, N = 512;
  __shared__ signed char As[2][128 * 64];
  __shared__ signed char Bs[2][64 * 64];
  const int t = threadIdx.x;
  const int lane = t & 63;
  const int w = t >> 6;
  const int wr = w >> 1, wc = w & 1;
  const int lin = blockIdx.x;
  const int xcd = lin & 7;
  const int bb = xcd >> 1;
  const int s = ((lin >> 3) << 1) | (xcd & 1);  // 0..127
  const int m0 = (bb * 16 + s / 8) * 128;
  const int n0 = (s % 8) * 64;

  i32x4 acc[4][2];
#pragma unroll
  for (int mi = 0; mi < 4; mi++)
#pragma unroll
    for (int ni = 0; ni < 2; ni++) {
      i32x4 z = {0, 0, 0, 0};
      acc[mi][ni] = z;
    }

  // A tile 128 rows x 64 B = 512 x 16B chunks (2/thread); B 64x64 B (1/thread).
  // Rows are 4 chunks; swizzle j^(r&3) (source pre-swizzled, read swizzled).
  auto stage = [&](int buf, int k0) {
#pragma unroll
    for (int i = 0; i < 2; i++) {
      const int c = t + i * 256;
      const int r = c >> 2, j = c & 3;
      GLD16(A + (long)(m0 + r) * K + k0 + ((j ^ (r & 3)) << 4), &As[buf][c * 16]);
    }
    {
      const int c = t;
      const int r = c >> 2, j = c & 3;
      GLD16(Bt + (long)(n0 + r) * K + k0 + ((j ^ (r & 3)) << 4), &Bs[buf][c * 16]);
    }
  };

  const int nt = K >> 6;  // 12
  stage(0, 0);
  for (int tt = 0; tt < nt; ++tt) {
    const int cur = tt & 1;
    if (tt + 1 < nt) {
      stage(cur ^ 1, (tt + 1) << 6);
      asm volatile("s_waitcnt vmcnt(3)" ::: "memory");
    } else {
      asm volatile("s_waitcnt vmcnt(0)" ::: "memory");
    }
    __builtin_amdgcn_s_barrier();

    __builtin_amdgcn_s_setprio(1);
    const int jj = lane >> 4;
    i32x4 af[4], bf[2];
#pragma unroll
    for (int mi = 0; mi < 4; mi++) {
      const int r = wr * 64 + mi * 16 + (lane & 15);
      af[mi] = *(const i32x4*)&As[cur][r * 64 + ((jj ^ (r & 3)) << 4)];
    }
#pragma unroll
    for (int ni = 0; ni < 2; ni++) {
      const int r = wc * 32 + ni * 16 + (lane & 15);
      bf[ni] = *(const i32x4*)&Bs[cur][r * 64 + ((jj ^ (r & 3)) << 4)];
    }
#pragma unroll
    for (int mi = 0; mi < 4; mi++)
#pragma unroll
      for (int ni = 0; ni < 2; ni++)
        acc[mi][ni] = __builtin_amdgcn_mfma_i32_16x16x64_i8(af[mi], bf[ni], acc[mi][ni], 0, 0, 0);
    __builtin_amdgcn_s_setprio(0);
    asm volatile("s_waitcnt lgkmcnt(0)" ::: "memory");
    __builtin_amdgcn_s_barrier();
  }

  const int lr = (lane >> 4) * 4;
  const int lc = lane & 15;
#pragma unroll
  for (int mi = 0; mi < 4; mi++) {
#pragma unroll
    for (int ni = 0; ni < 2; ni++) {
      const int col = n0 + wc * 32 + ni * 16 + lc;
      const float bvv = bias[col];
#pragma unroll
      for (int r = 0; r < 4; r++) {
        const int row = m0 + wr * 64 + mi * 16 + lr + r;
        C[(long)row * N + col] = f2bf((float)acc[mi][ni][r] * SCONST4 + bvv);
      }
    }
  }
}

// ---- attention: int8 q,k scores (sdot4, uint4 loads), uint8 v PV ----------
__global__ __launch_bounds__(256, 8) void k_attn(const signed char* __restrict__ qk8,
                                                 const unsigned char* __restrict__ v8,
                                                 const float* __restrict__ maskb,
                                                 const int* __restrict__ inxs,
                                                 unsigned short* __restrict__ att) {
  const int t = threadIdx.x;
  const int lane = t & 63;
  const int w = t >> 6;
  const int bid = blockIdx.x;
  const int xcd = bid & 7;
  const int b = xcd >> 1;
  const int sub = ((bid >> 3) << 1) | (xcd & 1);
  const int row = (b << 11) | (sub << 2) | w;
  const long base = (long)b * 2048;
  const int g = lane >> 4;
  const int li = lane & 15;
  const int kk = lane & 31;

  const int* ix = inxs + (long)row * 32;
  const int ixv = ix[kk];
  const float mval = maskb[(long)row * 32 + kk];

  const uint4* qp = (const uint4*)(qk8 + (long)row * 1024);
  uint4 qc[2];
#pragma unroll
  for (int c = 0; c < 2; c++) qc[c] = qp[li + c * 16];

  float scr[8];
#pragma unroll
  for (int r = 0; r < 8; r++) {
    const int nb = __shfl(ixv, r * 4 + g, 64);
    const uint4* kp = (const uint4*)(qk8 + (base + nb) * 1024 + 512);
    int di = 0;
#pragma unroll
    for (int c = 0; c < 2; c++) {
      const uint4 kc = kp[li + c * 16];
      di = __builtin_amdgcn_sdot4((int)kc.x, (int)qc[c].x, di, false);
      di = __builtin_amdgcn_sdot4((int)kc.y, (int)qc[c].y, di, false);
      di = __builtin_amdgcn_sdot4((int)kc.z, (int)qc[c].z, di, false);
      di = __builtin_amdgcn_sdot4((int)kc.w, (int)qc[c].w, di, false);
    }
#pragma unroll
    for (int m = 1; m <= 8; m <<= 1) di += __shfl_xor(di, m, 64);
    scr[r] = (float)di;
  }

  const int srcl = (kk & 3) << 4;
  float s = __shfl(scr[0], srcl, 64);
#pragma unroll
  for (int r = 1; r < 8; r++) {
    const float tr = __shfl(scr[r], srcl, 64);
    s = ((kk >> 2) == r) ? tr : s;
  }
  s = s * SCONST + mval;

  float mx = s;
#pragma unroll
  for (int d = 1; d <= 16; d <<= 1) mx = fmaxf(mx, __shfl_xor(mx, d, 64));
  const float e = __expf(s - mx);
  float ts = e;
#pragma unroll
  for (int d = 1; d <= 16; d <<= 1) ts += __shfl_xor(ts, d, 64);
  const float sinv = VSCALE / ts;

  float o[8] = {0, 0, 0, 0, 0, 0, 0, 0};
#pragma unroll
  for (int p = 0; p < 32; p++) {
    const int un = __shfl(ixv, p, 64);
    const float wn = __shfl(e, p, 64);
    const uint2 vv = *(const uint2*)(v8 + (base + un) * 512 + lane * 8);
    o[0] += wn * ub(vv.x, 0);
    o[1] += wn * ub(vv.x, 1);
    o[2] += wn * ub(vv.x, 2);
    o[3] += wn * ub(vv.x, 3);
    o[4] += wn * ub(vv.y, 0);
    o[5] += wn * ub(vv.y, 1);
    o[6] += wn * ub(vv.y, 2);
    o[7] += wn * ub(vv.y, 3);
  }

  short8 ov;
#pragma unroll
  for (int j = 0; j < 8; j++)
    ov[j] = (short)f2bf(o[j] * sinv - 128.f * VSCALE);
  *(short8*)(att + (long)row * 512 + lane * 8) = ov;
}

// ------- LN1: y = LN(xb_f16 + o_bf16) * g + beta, out bf16 ----------------
__global__ __launch_bounds__(256) void k_ln1(const unsigned short* __restrict__ xb,
                                             const unsigned short* __restrict__ o,
                                             const float* __restrict__ g,
                                             const float* __restrict__ beta,
                                             unsigned short* __restrict__ y) {
  const int lane = threadIdx.x & 63;
  const int w = threadIdx.x >> 6;
  const int bid = blockIdx.x;
  const int xcd = bid & 7;
  const int bb = xcd >> 1;
  const int s0 = ((bid >> 3) << 1) | (xcd & 1);
  const long row = ((long)bb << 11) | ((long)s0 << 2) | w;
  short8 xv = *(const short8*)(xb + row * 512 + lane * 8);
  short8 ov = *(const short8*)(o + row * 512 + lane * 8);
  float tv[8];
  float s = 0.f, s2 = 0.f;
#pragma unroll
  for (int j = 0; j < 8; j++) {
    tv[j] = h2f((unsigned short)xv[j]) + bf2f((unsigned short)ov[j]);
    s += tv[j];
    s2 += tv[j] * tv[j];
  }
#pragma unroll
  for (int m = 32; m >= 1; m >>= 1) {
    s += __shfl_xor(s, m, 64);
    s2 += __shfl_xor(s2, m, 64);
  }
  const float mean = s * (1.f / 512.f);
  const float var = s2 * (1.f / 512.f) - mean * mean;
  const float r = rsqrtf(var + 1e-5f);
  const float4* gp = (const float4*)(g + lane * 8);
  const float4* bp = (const float4*)(beta + lane * 8);
  float4 g0 = gp[0], g1v = gp[1], b0 = bp[0], b1 = bp[1];
  float gg[8] = {g0.x, g0.y, g0.z, g0.w, g1v.x, g1v.y, g1v.z, g1v.w};
  float bb2[8] = {b0.x, b0.y, b0.z, b0.w, b1.x, b1.y, b1.z, b1.w};
  short8 yv;
#pragma unroll
  for (int j = 0; j < 8; j++) yv[j] = (short)f2bf((tv[j] - mean) * r * gg[j] + bb2[j]);
  *(short8*)(y + row * 512 + lane * 8) = yv;
}

// ---------------- LN2: out_f32 = LN(y_bf16 + f_bf16) * g + beta -----------
__global__ __launch_bounds__(256) void k_ln2(const unsigned short* __restrict__ y,
                                             const unsigned short* __restrict__ f,
                                             const float* __restrict__ g,
                                             const float* __restrict__ beta,
                                             float* __restrict__ out) {
  const int lane = threadIdx.x & 63;
  const int w = threadIdx.x >> 6;
  const int bid = blockIdx.x;
  const int xcd = bid & 7;
  const int bb = xcd >> 1;
  const int s0 = ((bid >> 3) << 1) | (xcd & 1);
  const long row = ((long)bb << 11) | ((long)s0 << 2) | w;
  short8 yv = *(const short8*)(y + row * 512 + lane * 8);
  short8 fv = *(const short8*)(f + row * 512 + lane * 8);
  float tv[8];
  float s = 0.f, s2 = 0.f;
#pragma unroll
  for (int j = 0; j < 8; j++) {
    tv[j] = bf2f((unsigned short)yv[j]) + bf2f((unsigned short)fv[j]);
    s += tv[j];
    s2 += tv[j] * tv[j];
  }
#pragma unroll
  for (int m = 32; m >= 1; m >>= 1) {
    s += __shfl_xor(s, m, 64);
    s2 += __shfl_xor(s2, m, 64);
  }
  const float mean = s * (1.f / 512.f);
  const float var = s2 * (1.f / 512.f) - mean * mean;
  const float r = rsqrtf(var + 1e-5f);
  const float4* gp = (const float4*)(g + lane * 8);
  const float4* bp = (const float4*)(beta + lane * 8);
  float4 g0 = gp[0], g1v = gp[1], b0 = bp[0], b1 = bp[1];
  float gg[8] = {g0.x, g0.y, g0.z, g0.w, g1v.x, g1v.y, g1v.z, g1v.w};
  float bb2[8] = {b0.x, b0.y, b0.z, b0.w, b1.x, b1.y, b1.z, b1.w};
  float ovv[8];
#pragma unroll
  for (int j = 0; j < 8; j++) ovv[j] = (tv[j] - mean) * r * gg[j] + bb2[j];
  float4* op = (float4*)(out + row * 512 + lane * 8);
  float4 o0 = {ovv[0], ovv[1], ovv[2], ovv[3]};
  float4 o1 = {ovv[4], ovv[5], ovv[6], ovv[7]};
  op[0] = o0;
  op[1] = o1;
}

extern "C" void kernel_launch(void* const* d_in, const int* in_sizes, int n_in,
                              void* d_out, int out_size, void* d_ws, size_t ws_size,
                              hipStream_t stream) {
  const float* x   = (const float*)d_in[0];
  const float* adj = (const float*)d_in[1];
  const int*   inx = (const int*)d_in[2];
  const float* Wq  = (const float*)d_in[3];
  const float* bq  = (const float*)d_in[4];
  const float* Wk  = (const float*)d_in[5];
  const float* bk  = (const float*)d_in[6];
  const float* Wv  = (const float*)d_in[7];
  const float* bv  = (const float*)d_in[8];
  const float* Wo  = (const float*)d_in[9];
  const float* bo  = (const float*)d_in[10];
  const float* g1  = (const float*)d_in[11];
  const float* be1 = (const float*)d_in[12];
  const float* W1  = (const float*)d_in[13];
  const float* bf1 = (const float*)d_in[14];
  const float* W2  = (const float*)d_in[15];
  const float* bf2 = (const float*)d_in[16];
  const float* g2  = (const float*)d_in[17];
  const float* be2 = (const float*)d_in[18];

  // workspace (short units), ~56.5 MB. Aliases (stream-ordered safe):
  // h8<-qk8 (qk8 dead after attn); f<-oproj (dead after LN1);
  // w2t8 occupies the old w2t slot (needs half of it).
  unsigned short* xb    = (unsigned short*)d_ws;             // 4194304 (x f16)
  unsigned short* wqkvt = xb + 4194304;                      // 786432
  unsigned short* wot   = wqkvt + 786432;                    // 262144
  unsigned short* w1t   = wot + 262144;                      // 393216
  signed char*    w2t8  = (signed char*)(w1t + 393216);      // 393216 B (in 786432 B slot)
  signed char*    qk8   = (signed char*)(w1t + 393216 + 393216); // 8 MB
  unsigned char*  v8    = (unsigned char*)(qk8 + 8388608);   // 4 MB
  unsigned short* oproj = (unsigned short*)(v8 + 4194304);   // 4194304
  unsigned short* y     = oproj + 4194304;                   // 4194304
  float*          maskb = (float*)(y + 4194304);             // 1 MB
  unsigned short* att   = (unsigned short*)(maskb + 262144); // 4194304
  signed char*    h8    = qk8;                               // 8192*768 B fits
  unsigned short* f     = oproj;

  // prep: x->f16 + Wq/Wk/Wv transposes (only what G1x needs)
  k_prep<<<2816, 256, 0, stream>>>(x, xb, Wq, Wk, Wv, wqkvt);
  // G1x: qkv GEMM (1536 blocks, 128x64) + adj-mask + Wo/W1(bf16), W2(int8)
  k_g1x<<<3584, 256, 0, stream>>>(xb, wqkvt, bq, bk, bv, qk8, v8,
                                  adj, inx, maskb, Wo, W1, W2, wot, w1t, w2t8);
  // attention
  k_attn<<<2048, 256, 0, stream>>>(qk8, v8, maskb, inx, att);
  // G2: oproj = relu(att @ Wo + bo)
  k_gemm<1><<<512, 256, 0, stream>>>(att, wot, bo, oproj, 8192, 512, 512);
  // y = LN(xb + oproj)
  k_ln1<<<2048, 256, 0, stream>>>(xb, oproj, g1, be1, y);
  // G3: h8 = int8(relu(y @ W1 + bf1))
  k_gemm<2><<<768, 256, 0, stream>>>(y, w1t, bf1, (unsigned short*)h8, 8192, 768, 512);
  // G4: f = h8 @ W2^T (int8 MFMA) * SCONST4 + bf2
  k_gemm4<<<512, 256, 0, stream>>>(h8, w2t8, bf2, f);
  // out = LN(y + f)
  k_ln2<<<2048, 256, 0, stream>>>(y, f, g2, be2, (float*)d_out);
}

// Round 19
// 94.223 us; speedup vs baseline: 1.1631x; 1.0047x over previous
//
#include <hip/hip_runtime.h>
#include <stdint.h>

typedef __attribute__((ext_vector_type(8))) short short8;
typedef __attribute__((ext_vector_type(4))) float f32x4;
typedef __attribute__((ext_vector_type(4))) int i32x4;
typedef __attribute__((ext_vector_type(8))) _Float16 half8;

#define QSCALE 21.1666667f    /* 127/6 : activation quantize */
#define VSCALE 0.04724409449f /* 6/127 : v dequant */
#define SCONST 9.86413e-5f    /* (6/127)^2 / sqrt(512) : K=512 int8 dequant */
#define SCONST4 8.05405e-5f   /* (6/127)^2 / sqrt(768) : K=768 int8 dequant */
#define QW512 478.947f        /* 127*sqrt(512)/6 : W1 quantize */
#define QW2 586.589f          /* 127*sqrt(768)/6 : W2 quantize */

static __device__ __forceinline__ unsigned short f2bf(float f) {
  unsigned int u = __float_as_uint(f);
  u += 0x7FFFu + ((u >> 16) & 1u);
  return (unsigned short)(u >> 16);
}
static __device__ __forceinline__ float bf2f(unsigned short h) {
  return __uint_as_float(((unsigned int)h) << 16);
}
static __device__ __forceinline__ unsigned short f2h(float f) {
  _Float16 h = (_Float16)f;
  return __builtin_bit_cast(unsigned short, h);
}
static __device__ __forceinline__ float h2f(unsigned short h) {
  return (float)__builtin_bit_cast(_Float16, h);
}
static __device__ __forceinline__ signed char q8(float v) {
  float sv = fminf(fmaxf(v * QSCALE, -127.f), 127.f);
  return (signed char)(int)rintf(sv);
}
static __device__ __forceinline__ unsigned char qu8(float v) {
  return (unsigned char)(int)rintf(fminf(fmaxf(v * QSCALE + 128.f, 0.f), 255.f));
}
static __device__ __forceinline__ signed char qws(float v, float qs) {
  float sv = fminf(fmaxf(v * qs, -127.f), 127.f);
  return (signed char)(int)rintf(sv);
}
// LLVM pattern-matches this to v_cvt_f32_ubyteN
static __device__ __forceinline__ float ub(unsigned int x, int n) {
  return (float)((x >> (8 * n)) & 0xffu);
}

#define GLD16(gp, lp) __builtin_amdgcn_global_load_lds( \
    (__attribute__((address_space(1))) void*)(gp), \
    (__attribute__((address_space(3))) void*)(lp), 16, 0, 0)

// --------- prep: x->f16 (2048) | Wq/Wk/Wv transposes (768) -----------------
__global__ __launch_bounds__(256) void k_prep(
    const float* __restrict__ x, unsigned short* __restrict__ xb,
    const float* __restrict__ Wq, const float* __restrict__ Wk,
    const float* __restrict__ Wv, unsigned short* __restrict__ wqkvt) {
  __shared__ float tile[32][33];
  const int bid = blockIdx.x;
  const int t = threadIdx.x;
  if (bid < 2048) {
    const int xcd = bid & 7;
    const int bb = xcd >> 1;
    const int s = ((bid >> 3) << 1) | (xcd & 1);
    const long row = ((long)bb << 11) | ((long)s << 2) | (t >> 6);
    const int lane = t & 63;
    const float4* p = (const float4*)(x + row * 512 + lane * 8);
    float4 a = p[0], b = p[1];
    short8 v;
    v[0] = (short)f2h(a.x); v[1] = (short)f2h(a.y);
    v[2] = (short)f2h(a.z); v[3] = (short)f2h(a.w);
    v[4] = (short)f2h(b.x); v[5] = (short)f2h(b.y);
    v[6] = (short)f2h(b.z); v[7] = (short)f2h(b.w);
    *(short8*)(xb + row * 512 + lane * 8) = v;
    return;
  }
  const int lb = bid - 2048;       // 0..767
  const int m = lb >> 8;           // 0,1,2 -> Wq,Wk,Wv
  const float* src = m == 0 ? Wq : (m == 1 ? Wk : Wv);
  unsigned short* dst = wqkvt + (long)m * 512 * 512;
  const int local = lb & 255;
  const int c0 = (local & 15) << 5;
  const int r0 = (local >> 4) << 5;
  const int tx = t & 31, ty = t >> 5;
#pragma unroll
  for (int i = 0; i < 4; i++)
    tile[ty + i * 8][tx] = src[(long)(r0 + ty + i * 8) * 512 + c0 + tx];
  __syncthreads();
#pragma unroll
  for (int i = 0; i < 4; i++)
    dst[(long)(c0 + ty + i * 8) * 512 + r0 + tx] = f2h(tile[tx][ty + i * 8]);
}

// -- G1x: qkv GEMM 128x64/BK=64 (1536) | adj-mask (1024) | W transposes (1024)
// Wo -> bf16 (heavy-tailed att path stays bf16); W1/W2 -> int8.
__global__ __launch_bounds__(256) void k_g1x(
    const unsigned short* __restrict__ A, const unsigned short* __restrict__ Bt,
    const float* __restrict__ bq, const float* __restrict__ bk,
    const float* __restrict__ bv, signed char* __restrict__ qk8,
    unsigned char* __restrict__ v8,
    const float* __restrict__ adj, const int* __restrict__ inxs,
    float* __restrict__ maskb,
    const float* __restrict__ Wo, const float* __restrict__ W1,
    const float* __restrict__ W2, unsigned short* __restrict__ wot,
    signed char* __restrict__ w1t8, signed char* __restrict__ w2t8) {
  const int K = 512;
  __shared__ unsigned short As[2][128 * 64];
  __shared__ unsigned short Bs[2][64 * 64];
  const int t = threadIdx.x;
  const int bid = blockIdx.x;

  if (bid >= 1536) {
    const int eb = bid - 1536;
    if (eb < 1024) {
      // adj-mask gather: 8 rows/block, one lane per (row,kk)
      const int xcd = eb & 7;
      const int bb = xcd >> 1;
      const int s = ((eb >> 3) << 1) | (xcd & 1);
      const long row = ((long)bb << 11) | ((long)s << 3) | (t >> 5);
      const int kk = t & 31;
      const int idx = inxs[row * 32 + kk];
      const float a = adj[row * 2048 + idx];
      maskb[row * 32 + kk] = a > 0.f ? 0.f : -1e22f;
      return;
    }
    // Wo -> bf16 transpose; W1/W2 -> int8 transpose. 32x32 tiles.
    float(*tile)[33] = (float(*)[33]) & As[0][0];  // alias gemm LDS
    const int lb = eb - 1024;  // 0..1023
    const float* src;
    signed char* dst8 = nullptr;
    float qs = 0.f;
    int R, C, local, i8;
    if (lb < 256) { src = Wo; R = 512; C = 512; local = lb; i8 = 0; }
    else if (lb < 640) { src = W1; dst8 = w1t8; qs = QW512; R = 512; C = 768; local = lb - 256; i8 = 1; }
    else { src = W2; dst8 = w2t8; qs = QW2; R = 768; C = 512; local = lb - 640; i8 = 1; }
    const int ntx = C >> 5;
    const int c0 = (local % ntx) << 5;
    const int r0 = (local / ntx) << 5;
    const int tx = t & 31, ty = t >> 5;
#pragma unroll
    for (int i = 0; i < 4; i++)
      tile[ty + i * 8][tx] = src[(long)(r0 + ty + i * 8) * C + c0 + tx];
    __syncthreads();
    if (i8) {
#pragma unroll
      for (int i = 0; i < 4; i++)
        dst8[(long)(c0 + ty + i * 8) * R + r0 + tx] = qws(tile[tx][ty + i * 8], qs);
    } else {
#pragma unroll
      for (int i = 0; i < 4; i++)
        wot[(long)(c0 + ty + i * 8) * R + r0 + tx] = f2bf(tile[tx][ty + i * 8]);
    }
    return;
  }

  // ---------------- GEMM path (bid 0..1535): 128x64 tile, BK=64 -----------
  const int lane = t & 63;
  const int w = t >> 6;
  const int wr = w >> 1, wc = w & 1;
  const int xcd = bid & 7;
  const int bb = xcd >> 1;
  const int s = ((bid >> 3) << 1) | (xcd & 1);  // 0..383
  const int m0 = (bb * 16 + s / 24) * 128;
  const int n0 = (s % 24) * 64;

  f32x4 acc[4][2];
#pragma unroll
  for (int mi = 0; mi < 4; mi++)
#pragma unroll
    for (int ni = 0; ni < 2; ni++) {
      f32x4 z = {0.f, 0.f, 0.f, 0.f};
      acc[mi][ni] = z;
    }

  auto stage = [&](int buf, int k0) {
#pragma unroll
    for (int i = 0; i < 4; i++) {
      const int c = t + i * 256;
      const int r = c >> 3, j = c & 7;
      GLD16(A + (long)(m0 + r) * K + k0 + ((j ^ (r & 7)) << 3), &As[buf][c * 8]);
    }
#pragma unroll
    for (int i = 0; i < 2; i++) {
      const int c = t + i * 256;
      const int r = c >> 3, j = c & 7;
      GLD16(Bt + (long)(n0 + r) * K + k0 + ((j ^ (r & 7)) << 3), &Bs[buf][c * 8]);
    }
  };

  const int nt = K >> 6;  // 8
  stage(0, 0);
  for (int tt = 0; tt < nt; ++tt) {
    const int cur = tt & 1;
    if (tt + 1 < nt) {
      stage(cur ^ 1, (tt + 1) << 6);
      asm volatile("s_waitcnt vmcnt(6)" ::: "memory");
    } else {
      asm volatile("s_waitcnt vmcnt(0)" ::: "memory");
    }
    __builtin_amdgcn_s_barrier();

    __builtin_amdgcn_s_setprio(1);
#pragma unroll
    for (int kk = 0; kk < 2; kk++) {
      short8 af[4], bf[2];
#pragma unroll
      for (int mi = 0; mi < 4; mi++) {
        const int r = wr * 64 + mi * 16 + (lane & 15);
        const int jj = (kk << 2) + (lane >> 4);
        af[mi] = *(const short8*)&As[cur][r * 64 + ((jj ^ (r & 7)) << 3)];
      }
#pragma unroll
      for (int ni = 0; ni < 2; ni++) {
        const int r = wc * 32 + ni * 16 + (lane & 15);
        const int jj = (kk << 2) + (lane >> 4);
        bf[ni] = *(const short8*)&Bs[cur][r * 64 + ((jj ^ (r & 7)) << 3)];
      }
#pragma unroll
      for (int mi = 0; mi < 4; mi++)
#pragma unroll
        for (int ni = 0; ni < 2; ni++)
          acc[mi][ni] = __builtin_amdgcn_mfma_f32_16x16x32_f16(
              __builtin_bit_cast(half8, af[mi]), __builtin_bit_cast(half8, bf[ni]),
              acc[mi][ni], 0, 0, 0);
    }
    __builtin_amdgcn_s_setprio(0);
    asm volatile("s_waitcnt lgkmcnt(0)" ::: "memory");
    __builtin_amdgcn_s_barrier();
  }

  const int lr = (lane >> 4) * 4;
  const int lc = lane & 15;
  if (n0 < 1024) {  // q,k -> int8
#pragma unroll
    for (int mi = 0; mi < 4; mi++) {
#pragma unroll
      for (int ni = 0; ni < 2; ni++) {
        const int col = n0 + wc * 32 + ni * 16 + lc;
        const float bvv = col < 512 ? bq[col] : bk[col - 512];
#pragma unroll
        for (int r = 0; r < 4; r++) {
          const int row = m0 + wr * 64 + mi * 16 + lr + r;
          qk8[(long)row * 1024 + col] = q8(acc[mi][ni][r] + bvv);
        }
      }
    }
  } else {  // v -> uint8 fixed scale, bias 128
#pragma unroll
    for (int mi = 0; mi < 4; mi++) {
#pragma unroll
      for (int ni = 0; ni < 2; ni++) {
        const int col = n0 + wc * 32 + ni * 16 + lc;
        const float bvv = bv[col - 1024];
#pragma unroll
        for (int r = 0; r < 4; r++) {
          const int row = m0 + wr * 64 + mi * 16 + lr + r;
          v8[(long)row * 512 + (col - 1024)] = qu8(acc[mi][ni][r] + bvv);
        }
      }
    }
  }
}

// ------- bf16 MFMA GEMM, 128x64 tile, BK=64, dbuf + counted vmcnt ---------
// EPI: 0 = bias, 1 = bias+relu.
template <int EPI>
__global__ __launch_bounds__(256) void k_gemm(const unsigned short* __restrict__ A,
                                              const unsigned short* __restrict__ Bt,
                                              const float* __restrict__ bias,
                                              unsigned short* __restrict__ C,
                                              int M, int N, int K) {
  __shared__ unsigned short As[2][128 * 64];
  __shared__ unsigned short Bs[2][64 * 64];
  const int t = threadIdx.x;
  const int lane = t & 63;
  const int w = t >> 6;
  const int wr = w >> 1, wc = w & 1;
  const int lin = blockIdx.x;
  const int xcd = lin & 7;
  const int bb = xcd >> 1;
  const int nx = N >> 6;
  const int s = ((lin >> 3) << 1) | (xcd & 1);
  const int m0 = (bb * 16 + s / nx) * 128;
  const int n0 = (s % nx) * 64;

  f32x4 acc[4][2];
#pragma unroll
  for (int mi = 0; mi < 4; mi++)
#pragma unroll
    for (int ni = 0; ni < 2; ni++) {
      f32x4 z = {0.f, 0.f, 0.f, 0.f};
      acc[mi][ni] = z;
    }

  auto stage = [&](int buf, int k0) {
#pragma unroll
    for (int i = 0; i < 4; i++) {
      const int c = t + i * 256;
      const int r = c >> 3, j = c & 7;
      GLD16(A + (long)(m0 + r) * K + k0 + ((j ^ (r & 7)) << 3), &As[buf][c * 8]);
    }
#pragma unroll
    for (int i = 0; i < 2; i++) {
      const int c = t + i * 256;
      const int r = c >> 3, j = c & 7;
      GLD16(Bt + (long)(n0 + r) * K + k0 + ((j ^ (r & 7)) << 3), &Bs[buf][c * 8]);
    }
  };

  const int nt = K >> 6;
  stage(0, 0);
  for (int tt = 0; tt < nt; ++tt) {
    const int cur = tt & 1;
    if (tt + 1 < nt) {
      stage(cur ^ 1, (tt + 1) << 6);
      asm volatile("s_waitcnt vmcnt(6)" ::: "memory");
    } else {
      asm volatile("s_waitcnt vmcnt(0)" ::: "memory");
    }
    __builtin_amdgcn_s_barrier();

    __builtin_amdgcn_s_setprio(1);
#pragma unroll
    for (int kk = 0; kk < 2; kk++) {
      short8 af[4], bf[2];
#pragma unroll
      for (int mi = 0; mi < 4; mi++) {
        const int r = wr * 64 + mi * 16 + (lane & 15);
        const int jj = (kk << 2) + (lane >> 4);
        af[mi] = *(const short8*)&As[cur][r * 64 + ((jj ^ (r & 7)) << 3)];
      }
#pragma unroll
      for (int ni = 0; ni < 2; ni++) {
        const int r = wc * 32 + ni * 16 + (lane & 15);
        const int jj = (kk << 2) + (lane >> 4);
        bf[ni] = *(const short8*)&Bs[cur][r * 64 + ((jj ^ (r & 7)) << 3)];
      }
#pragma unroll
      for (int mi = 0; mi < 4; mi++)
#pragma unroll
        for (int ni = 0; ni < 2; ni++)
          acc[mi][ni] = __builtin_amdgcn_mfma_f32_16x16x32_bf16(af[mi], bf[ni], acc[mi][ni], 0, 0, 0);
    }
    __builtin_amdgcn_s_setprio(0);
    asm volatile("s_waitcnt lgkmcnt(0)" ::: "memory");
    __builtin_amdgcn_s_barrier();
  }

  const int lr = (lane >> 4) * 4;
  const int lc = lane & 15;
#pragma unroll
  for (int mi = 0; mi < 4; mi++) {
#pragma unroll
    for (int ni = 0; ni < 2; ni++) {
      const int col = n0 + wc * 32 + ni * 16 + lc;
      const float bvv = bias[col];
#pragma unroll
      for (int r = 0; r < 4; r++) {
        const int row = m0 + wr * 64 + mi * 16 + lr + r;
        float v = acc[mi][ni][r] + bvv;
        if (EPI == 1) v = fmaxf(v, 0.f);
        C[(long)row * N + col] = f2bf(v);
      }
    }
  }
}

// ------- generic int8 MFMA GEMM, 128x64 tile, BK=64, dbuf, 24 KB LDS ------
// C[M,N] = (A8[M,K] @ Bt8[N,K]^T) * dq + bias.
// EPI: 0 = bf16 out, 2 = relu + int8-quant out.
template <int EPI>
__global__ __launch_bounds__(256) void k_gemm8(const signed char* __restrict__ A,
                                               const signed char* __restrict__ Bt,
                                               const float* __restrict__ bias,
                                               unsigned short* __restrict__ C,
                                               int M, int N, int K, float dq) {
  __shared__ signed char As[2][128 * 64];
  __shared__ signed char Bs[2][64 * 64];
  const int t = threadIdx.x;
  const int lane = t & 63;
  const int w = t >> 6;
  const int wr = w >> 1, wc = w & 1;
  const int lin = blockIdx.x;
  const int xcd = lin & 7;
  const int bb = xcd >> 1;
  const int nx = N >> 6;
  const int s = ((lin >> 3) << 1) | (xcd & 1);
  const int m0 = (bb * 16 + s / nx) * 128;
  const int n0 = (s % nx) * 64;

  i32x4 acc[4][2];
#pragma unroll
  for (int mi = 0; mi < 4; mi++)
#pragma unroll
    for (int ni = 0; ni < 2; ni++) {
      i32x4 z = {0, 0, 0, 0};
      acc[mi][ni] = z;
    }

  auto stage = [&](int buf, int k0) {
#pragma unroll
    for (int i = 0; i < 2; i++) {
      const int c = t + i * 256;
      const int r = c >> 2, j = c & 3;
      GLD16(A + (long)(m0 + r) * K + k0 + ((j ^ (r & 3)) << 4), &As[buf][c * 16]);
    }
    {
      const int c = t;
      const int r = c >> 2, j = c & 3;
      GLD16(Bt + (long)(n0 + r) * K + k0 + ((j ^ (r & 3)) << 4), &Bs[buf][c * 16]);
    }
  };

  const int nt = K >> 6;
  stage(0, 0);
  for (int tt = 0; tt < nt; ++tt) {
    const int cur = tt & 1;
    if (tt + 1 < nt) {
      stage(cur ^ 1, (tt + 1) << 6);
      asm volatile("s_waitcnt vmcnt(3)" ::: "memory");
    } else {
      asm volatile("s_waitcnt vmcnt(0)" ::: "memory");
    }
    __builtin_amdgcn_s_barrier();

    __builtin_amdgcn_s_setprio(1);
    const int jj = lane >> 4;
    i32x4 af[4], bf[2];
#pragma unroll
    for (int mi = 0; mi < 4; mi++) {
      const int r = wr * 64 + mi * 16 + (lane & 15);
      af[mi] = *(const i32x4*)&As[cur][r * 64 + ((jj ^ (r & 3)) << 4)];
    }
#pragma unroll
    for (int ni = 0; ni < 2; ni++) {
      const int r = wc * 32 + ni * 16 + (lane & 15);
      bf[ni] = *(const i32x4*)&Bs[cur][r * 64 + ((jj ^ (r & 3)) << 4)];
    }
#pragma unroll
    for (int mi = 0; mi < 4; mi++)
#pragma unroll
      for (int ni = 0; ni < 2; ni++)
        acc[mi][ni] = __builtin_amdgcn_mfma_i32_16x16x64_i8(af[mi], bf[ni], acc[mi][ni], 0, 0, 0);
    __builtin_amdgcn_s_setprio(0);
    asm volatile("s_waitcnt lgkmcnt(0)" ::: "memory");
    __builtin_amdgcn_s_barrier();
  }

  const int lr = (lane >> 4) * 4;
  const int lc = lane & 15;
#pragma unroll
  for (int mi = 0; mi < 4; mi++) {
#pragma unroll
    for (int ni = 0; ni < 2; ni++) {
      const int col = n0 + wc * 32 + ni * 16 + lc;
      const float bvv = bias[col];
#pragma unroll
      for (int r = 0; r < 4; r++) {
        const int row = m0 + wr * 64 + mi * 16 + lr + r;
        float v = (float)acc[mi][ni][r] * dq + bvv;
        if (EPI == 2) {
          ((signed char*)C)[(long)row * N + col] =
              (signed char)(int)rintf(fminf(fmaxf(v, 0.f) * QSCALE, 127.f));
        } else {
          C[(long)row * N + col] = f2bf(v);
        }
      }
    }
  }
}

// ---- attention: int8 q,k scores (sdot4), uint8 v PV; bf16 att out --------
__global__ __launch_bounds__(256, 8) void k_attn(const signed char* __restrict__ qk8,
                                                 const unsigned char* __restrict__ v8,
                                                 const float* __restrict__ maskb,
                                                 const int* __restrict__ inxs,
                                                 unsigned short* __restrict__ att) {
  const int t = threadIdx.x;
  const int lane = t & 63;
  const int w = t >> 6;
  const int bid = blockIdx.x;
  const int xcd = bid & 7;
  const int b = xcd >> 1;
  const int sub = ((bid >> 3) << 1) | (xcd & 1);
  const int row = (b << 11) | (sub << 2) | w;
  const long base = (long)b * 2048;
  const int g = lane >> 4;
  const int li = lane & 15;
  const int kk = lane & 31;

  const int* ix = inxs + (long)row * 32;
  const int ixv = ix[kk];
  const float mval = maskb[(long)row * 32 + kk];

  const uint4* qp = (const uint4*)(qk8 + (long)row * 1024);
  uint4 qc[2];
#pragma unroll
  for (int c = 0; c < 2; c++) qc[c] = qp[li + c * 16];

  float scr[8];
#pragma unroll
  for (int r = 0; r < 8; r++) {
    const int nb = __shfl(ixv, r * 4 + g, 64);
    const uint4* kp = (const uint4*)(qk8 + (base + nb) * 1024 + 512);
    int di = 0;
#pragma unroll
    for (int c = 0; c < 2; c++) {
      const uint4 kc = kp[li + c * 16];
      di = __builtin_amdgcn_sdot4((int)kc.x, (int)qc[c].x, di, false);
      di = __builtin_amdgcn_sdot4((int)kc.y, (int)qc[c].y, di, false);
      di = __builtin_amdgcn_sdot4((int)kc.z, (int)qc[c].z, di, false);
      di = __builtin_amdgcn_sdot4((int)kc.w, (int)qc[c].w, di, false);
    }
#pragma unroll
    for (int m = 1; m <= 8; m <<= 1) di += __shfl_xor(di, m, 64);
    scr[r] = (float)di;
  }

  const int srcl = (kk & 3) << 4;
  float s = __shfl(scr[0], srcl, 64);
#pragma unroll
  for (int r = 1; r < 8; r++) {
    const float tr = __shfl(scr[r], srcl, 64);
    s = ((kk >> 2) == r) ? tr : s;
  }
  s = s * SCONST + mval;

  float mx = s;
#pragma unroll
  for (int d = 1; d <= 16; d <<= 1) mx = fmaxf(mx, __shfl_xor(mx, d, 64));
  const float e = __expf(s - mx);
  float ts = e;
#pragma unroll
  for (int d = 1; d <= 16; d <<= 1) ts += __shfl_xor(ts, d, 64);
  const float sinv = VSCALE / ts;

  float o[8] = {0, 0, 0, 0, 0, 0, 0, 0};
#pragma unroll
  for (int p = 0; p < 32; p++) {
    const int un = __shfl(ixv, p, 64);
    const float wn = __shfl(e, p, 64);
    const uint2 vv = *(const uint2*)(v8 + (base + un) * 512 + lane * 8);
    o[0] += wn * ub(vv.x, 0);
    o[1] += wn * ub(vv.x, 1);
    o[2] += wn * ub(vv.x, 2);
    o[3] += wn * ub(vv.x, 3);
    o[4] += wn * ub(vv.y, 0);
    o[5] += wn * ub(vv.y, 1);
    o[6] += wn * ub(vv.y, 2);
    o[7] += wn * ub(vv.y, 3);
  }

  short8 ov;
#pragma unroll
  for (int j = 0; j < 8; j++)
    ov[j] = (short)f2bf(o[j] * sinv - 128.f * VSCALE);
  *(short8*)(att + (long)row * 512 + lane * 8) = ov;
}

// --- LN1: y = LN(xb_f16 + o_bf16) * g + beta -> y (bf16) and y8 (int8) ----
__global__ __launch_bounds__(256) void k_ln1(const unsigned short* __restrict__ xb,
                                             const unsigned short* __restrict__ o,
                                             const float* __restrict__ g,
                                             const float* __restrict__ beta,
                                             unsigned short* __restrict__ y,
                                             signed char* __restrict__ y8) {
  const int lane = threadIdx.x & 63;
  const int w = threadIdx.x >> 6;
  const int bid = blockIdx.x;
  const int xcd = bid & 7;
  const int bb = xcd >> 1;
  const int s0 = ((bid >> 3) << 1) | (xcd & 1);
  const long row = ((long)bb << 11) | ((long)s0 << 2) | w;
  short8 xv = *(const short8*)(xb + row * 512 + lane * 8);
  short8 ov = *(const short8*)(o + row * 512 + lane * 8);
  float tv[8];
  float s = 0.f, s2 = 0.f;
#pragma unroll
  for (int j = 0; j < 8; j++) {
    tv[j] = h2f((unsigned short)xv[j]) + bf2f((unsigned short)ov[j]);
    s += tv[j];
    s2 += tv[j] * tv[j];
  }
#pragma unroll
  for (int m = 32; m >= 1; m >>= 1) {
    s += __shfl_xor(s, m, 64);
    s2 += __shfl_xor(s2, m, 64);
  }
  const float mean = s * (1.f / 512.f);
  const float var = s2 * (1.f / 512.f) - mean * mean;
  const float r = rsqrtf(var + 1e-5f);
  const float4* gp = (const float4*)(g + lane * 8);
  const float4* bp = (const float4*)(beta + lane * 8);
  float4 g0 = gp[0], g1v = gp[1], b0 = bp[0], b1 = bp[1];
  float gg[8] = {g0.x, g0.y, g0.z, g0.w, g1v.x, g1v.y, g1v.z, g1v.w};
  float bb2[8] = {b0.x, b0.y, b0.z, b0.w, b1.x, b1.y, b1.z, b1.w};
  short8 yv;
  unsigned int w0 = 0, w1v = 0;
#pragma unroll
  for (int j = 0; j < 8; j++) {
    const float val = (tv[j] - mean) * r * gg[j] + bb2[j];
    yv[j] = (short)f2bf(val);
    const unsigned int qb = (unsigned int)(unsigned char)q8(val);
    if (j < 4) w0 |= qb << (8 * j);
    else w1v |= qb << (8 * (j - 4));
  }
  *(short8*)(y + row * 512 + lane * 8) = yv;
  uint2 pw = {w0, w1v};
  *(uint2*)(y8 + row * 512 + lane * 8) = pw;
}

// ---------------- LN2: out_f32 = LN(y_bf16 + f_bf16) * g + beta -----------
__global__ __launch_bounds__(256) void k_ln2(const unsigned short* __restrict__ y,
                                             const unsigned short* __restrict__ f,
                                             const float* __restrict__ g,
                                             const float* __restrict__ beta,
                                             float* __restrict__ out) {
  const int lane = threadIdx.x & 63;
  const int w = threadIdx.x >> 6;
  const int bid = blockIdx.x;
  const int xcd = bid & 7;
  const int bb = xcd >> 1;
  const int s0 = ((bid >> 3) << 1) | (xcd & 1);
  const long row = ((long)bb << 11) | ((long)s0 << 2) | w;
  short8 yv = *(const short8*)(y + row * 512 + lane * 8);
  short8 fv = *(const short8*)(f + row * 512 + lane * 8);
  float tv[8];
  float s = 0.f, s2 = 0.f;
#pragma unroll
  for (int j = 0; j < 8; j++) {
    tv[j] = bf2f((unsigned short)yv[j]) + bf2f((unsigned short)fv[j]);
    s += tv[j];
    s2 += tv[j] * tv[j];
  }
#pragma unroll
  for (int m = 32; m >= 1; m >>= 1) {
    s += __shfl_xor(s, m, 64);
    s2 += __shfl_xor(s2, m, 64);
  }
  const float mean = s * (1.f / 512.f);
  const float var = s2 * (1.f / 512.f) - mean * mean;
  const float r = rsqrtf(var + 1e-5f);
  const float4* gp = (const float4*)(g + lane * 8);
  const float4* bp = (const float4*)(beta + lane * 8);
  float4 g0 = gp[0], g1v = gp[1], b0 = bp[0], b1 = bp[1];
  float gg[8] = {g0.x, g0.y, g0.z, g0.w, g1v.x, g1v.y, g1v.z, g1v.w};
  float bb2[8] = {b0.x, b0.y, b0.z, b0.w, b1.x, b1.y, b1.z, b1.w};
  float ovv[8];
#pragma unroll
  for (int j = 0; j < 8; j++) ovv[j] = (tv[j] - mean) * r * gg[j] + bb2[j];
  float4* op = (float4*)(out + row * 512 + lane * 8);
  float4 o0 = {ovv[0], ovv[1], ovv[2], ovv[3]};
  float4 o1 = {ovv[4], ovv[5], ovv[6], ovv[7]};
  op[0] = o0;
  op[1] = o1;
}

extern "C" void kernel_launch(void* const* d_in, const int* in_sizes, int n_in,
                              void* d_out, int out_size, void* d_ws, size_t ws_size,
                              hipStream_t stream) {
  const float* x   = (const float*)d_in[0];
  const float* adj = (const float*)d_in[1];
  const int*   inx = (const int*)d_in[2];
  const float* Wq  = (const float*)d_in[3];
  const float* bq  = (const float*)d_in[4];
  const float* Wk  = (const float*)d_in[5];
  const float* bk  = (const float*)d_in[6];
  const float* Wv  = (const float*)d_in[7];
  const float* bv  = (const float*)d_in[8];
  const float* Wo  = (const float*)d_in[9];
  const float* bo  = (const float*)d_in[10];
  const float* g1  = (const float*)d_in[11];
  const float* be1 = (const float*)d_in[12];
  const float* W1  = (const float*)d_in[13];
  const float* bf1 = (const float*)d_in[14];
  const float* W2  = (const float*)d_in[15];
  const float* bf2 = (const float*)d_in[16];
  const float* g2  = (const float*)d_in[17];
  const float* be2 = (const float*)d_in[18];

  // workspace layout (bytes), ~53 MB. Aliases (stream-ordered safe):
  // h8<-qk8 (qk8 dead after attn); f<-oproj (dead after LN1).
  unsigned char* ws = (unsigned char*)d_ws;
  unsigned short* xb    = (unsigned short*)ws;             // 8 MB (x f16)
  unsigned short* wqkvt = (unsigned short*)(ws + 8388608); // 1.5 MB
  unsigned short* wot   = (unsigned short*)(ws + 9961472); // 512 KB (bf16)
  signed char*    w1t8  = (signed char*)(ws + 10485760);   // 384 KB
  signed char*    w2t8  = w1t8 + 393216;                   // 384 KB
  signed char*    qk8   = w2t8 + 393216;                   // 8 MB
  unsigned char*  v8    = (unsigned char*)(qk8 + 8388608); // 4 MB
  unsigned short* oproj = (unsigned short*)(v8 + 4194304); // 8 MB
  unsigned short* y     = oproj + 4194304;                 // 8 MB
  signed char*    y8    = (signed char*)(y + 4194304);     // 4 MB
  float*          maskb = (float*)(y8 + 4194304);          // 1 MB
  unsigned short* att   = (unsigned short*)(maskb + 262144); // 8 MB (bf16)
  signed char*    h8    = qk8;                             // 6 MB fits in 8
  unsigned short* f     = oproj;

  // prep: x->f16 + Wq/Wk/Wv transposes
  k_prep<<<2816, 256, 0, stream>>>(x, xb, Wq, Wk, Wv, wqkvt);
  // G1x: qkv GEMM + adj-mask + Wo(bf16)/W1,W2(int8) transposes
  k_g1x<<<3584, 256, 0, stream>>>(xb, wqkvt, bq, bk, bv, qk8, v8,
                                  adj, inx, maskb, Wo, W1, W2, wot, w1t8, w2t8);
  // attention -> bf16 att
  k_attn<<<2048, 256, 0, stream>>>(qk8, v8, maskb, inx, att);
  // G2: oproj = relu(att @ Wo + bo)   (bf16 MFMA — heavy-tailed att stays bf16)
  k_gemm<1><<<512, 256, 0, stream>>>(att, wot, bo, oproj, 8192, 512, 512);
  // y,y8 = LN(xb + oproj)
  k_ln1<<<2048, 256, 0, stream>>>(xb, oproj, g1, be1, y, y8);
  // G3: h8 = int8(relu(y8 @ w1t8 * SCONST + bf1))   (int8 MFMA)
  k_gemm8<2><<<768, 256, 0, stream>>>(y8, w1t8, bf1, (unsigned short*)h8, 8192, 768, 512, SCONST);
  // G4: f = h8 @ w2t8 * SCONST4 + bf2   (int8 MFMA)
  k_gemm8<0><<<512, 256, 0, stream>>>(h8, w2t8, bf2, f, 8192, 512, 768, SCONST4);
  // out = LN(y + f)
  k_ln2<<<2048, 256, 0, stream>>>(y, f, g2, be2, (float*)d_out);
}